// Round 5
// baseline (1679.301 us; speedup 1.0000x reference)
//
#include <hip/hip_runtime.h>
#include <hip/hip_fp16.h>

typedef __attribute__((ext_vector_type(8))) short short8;
typedef __attribute__((ext_vector_type(4))) float f32x4;
typedef unsigned short u16;

__device__ __forceinline__ u16 f2bf(float f) {
    unsigned u = __float_as_uint(f);
    unsigned r = ((u >> 16) & 1) + 0x7FFFu;
    return (u16)((u + r) >> 16);
}

__device__ __forceinline__ void gload_lds16(const void* g, void* l) {
    __builtin_amdgcn_global_load_lds((const __attribute__((address_space(1))) unsigned int*)g,
                                     (__attribute__((address_space(3))) unsigned int*)l,
                                     16, 0, 0);
}

// ---------------- CSR build kernels ----------------

__global__ void k_count(const int* __restrict__ dst, int* __restrict__ cnt, int E) {
    int i = blockIdx.x * 256 + threadIdx.x;
    if (i < E) atomicAdd(&cnt[dst[i]], 1);
}

__global__ void k_scan1(const int* __restrict__ cnt, int* __restrict__ partial, int N) {
    __shared__ int sm[256];
    int idx = blockIdx.x * 256 + threadIdx.x;
    sm[threadIdx.x] = (idx < N) ? cnt[idx] : 0;
    __syncthreads();
    for (int s = 128; s > 0; s >>= 1) {
        if (threadIdx.x < s) sm[threadIdx.x] += sm[threadIdx.x + s];
        __syncthreads();
    }
    if (threadIdx.x == 0) partial[blockIdx.x] = sm[0];
}

__global__ void k_scan2(int* __restrict__ partial, int nb) {
    __shared__ int sm[512];
    int t = threadIdx.x;
    sm[t] = (t < nb) ? partial[t] : 0;
    __syncthreads();
    for (int off = 1; off < 512; off <<= 1) {
        int v = (t >= off) ? sm[t - off] : 0;
        __syncthreads();
        sm[t] += v;
        __syncthreads();
    }
    if (t < nb) partial[t] = (t == 0) ? 0 : sm[t - 1];  // exclusive
}

__global__ void k_scan3(const int* __restrict__ cnt, const int* __restrict__ partial,
                        int* __restrict__ row_off, int* __restrict__ cursor,
                        float* __restrict__ invdeg, int N, int E) {
    __shared__ int sm[256];
    int idx = blockIdx.x * 256 + threadIdx.x;
    int v = (idx < N) ? cnt[idx] : 0;
    sm[threadIdx.x] = v;
    __syncthreads();
    for (int off = 1; off < 256; off <<= 1) {
        int u = (threadIdx.x >= off) ? sm[threadIdx.x - off] : 0;
        __syncthreads();
        sm[threadIdx.x] += u;
        __syncthreads();
    }
    if (idx < N) {
        int excl = partial[blockIdx.x] + sm[threadIdx.x] - v;
        row_off[idx] = excl;
        cursor[idx] = excl;
        invdeg[idx] = 1.0f / (float)((v > 1) ? v : 1);
    }
    if (idx == 0) row_off[N] = E;
}

// scatter edge payload into CSR slots: {src, si, di, rv} + dst per slot
__global__ void k_scatter(const int* __restrict__ dst, const int* __restrict__ src,
                          const float* __restrict__ sidx, const float* __restrict__ didx,
                          const float* __restrict__ rev,
                          int* __restrict__ cursor, int4* __restrict__ payload,
                          int* __restrict__ edst, int E) {
    int i = blockIdx.x * 256 + threadIdx.x;
    if (i < E) {
        int d = dst[i];
        int p = atomicAdd(&cursor[d], 1);
        int4 v;
        v.x = src[i];
        v.y = __float_as_int(sidx[i]);
        v.z = __float_as_int(didx[i]);
        v.w = __float_as_int(rev[i]);
        payload[p] = v;
        edst[p] = d;
    }
}

// ---------------- embedding gather (bf16 out) ----------------

__global__ void k_emb(const int* __restrict__ gt, const float* __restrict__ emb,
                      u16* __restrict__ h0, int N) {
    int i = blockIdx.x * 256 + threadIdx.x;
    if (i < N * 64) {
        int n = i >> 6, f = i & 63;
        h0[i] = f2bf(emb[(gt[n] << 6) | f]);
    }
}

// ---------------- weight fp32 -> bf16 dense conversion ----------------

struct WDesc {
    const float* src[10];
    u16* dst[10];
    int scols[10];
    int dcols[10];
    int n[10];
};

__global__ void k_wconv(WDesc d) {
    int seg = blockIdx.y;
    int idx = blockIdx.x * 256 + threadIdx.x;
    if (idx < d.n[seg]) {
        int dc = d.dcols[seg];
        int r = idx / dc, c = idx % dc;
        d.dst[seg][idx] = f2bf(d.src[seg][r * d.scols[seg] + c]);
    }
}

// ---------------- edge aggregation: edge-slab + LDS accumulate ----------------
// Block owns 32 consecutive dst nodes -> contiguous CSR edge range.
// 4 waves split the range into contiguous chunks (edge-balanced).
// lane covers feats (2*lane, 2*lane+1); depth-2 pipeline; ds_add_f32 accumulate.

__global__ __launch_bounds__(256)
void k_edge(int N, int fi,
            const int* __restrict__ row_off, const int4* __restrict__ payload,
            const int* __restrict__ edst,
            const u16* __restrict__ g,        // [N,128] fp16
            const float* __restrict__ W1,     // [128, fi+3] fp32 original
            const float* __restrict__ invdeg,
            u16* __restrict__ hN)             // [N,128] bf16
{
    __shared__ float acc[32 * 128];
    const int t = threadIdx.x;
    const int lane = t & 63;
    const int w = t >> 6;
    const int n0 = blockIdx.x * 32;
    const int ldw1 = fi + 3;
    const float* wr0 = W1 + (size_t)(2 * lane) * ldw1 + fi;
    const float* wr1 = W1 + (size_t)(2 * lane + 1) * ldw1 + fi;
    const float w00 = wr0[0], w01 = wr0[1], w02 = wr0[2];
    const float w10 = wr1[0], w11 = wr1[1], w12 = wr1[2];

#pragma unroll
    for (int i = 0; i < 16; i++) acc[t + 256 * i] = 0.f;

    const int nEnd = (n0 + 32 < N) ? (n0 + 32) : N;
    const int beg = row_off[n0];
    const int end = row_off[nEnd];
    __syncthreads();

    const int cnt = end - beg;
    const int chunk = (cnt + 3) >> 2;
    const int s0 = beg + w * chunk;
    int s1 = s0 + chunk;
    if (s1 > end) s1 = end;
    const int myc = s1 - s0;

    if (myc > 0) {
        int4 plA = payload[s0];
        int ndA = edst[s0] - n0;
        unsigned gvA = *(const unsigned*)(g + ((size_t)plA.x << 7) + (lane << 1));
        int4 plB = plA;
        int ndB = ndA;
        unsigned gvB = gvA;
        if (myc > 1) {
            plB = payload[s0 + 1];
            ndB = edst[s0 + 1] - n0;
            gvB = *(const unsigned*)(g + ((size_t)plB.x << 7) + (lane << 1));
        }
        for (int j = 0; j < myc; ++j) {
            const float si = __int_as_float(plA.y);
            const float di = __int_as_float(plA.z);
            const float rv = __int_as_float(plA.w);
            const float2 f = __half22float2(*(const __half2*)&gvA);
            const int nd = ndA;
            plA = plB; gvA = gvB; ndA = ndB;
            if (j + 2 < myc) {
                plB = payload[s0 + j + 2];
                ndB = edst[s0 + j + 2] - n0;
                gvB = *(const unsigned*)(g + ((size_t)plB.x << 7) + (lane << 1));
            }
            float v0 = f.x + w00 * si + w01 * di + w02 * rv;
            float v1 = f.y + w10 * si + w11 * di + w12 * rv;
            v0 = fmaxf(v0, 0.f) + 0.01f * fminf(v0, 0.f);
            v1 = fmaxf(v1, 0.f) + 0.01f * fminf(v1, 0.f);
            float* ap = &acc[nd * 128 + (lane << 1)];
            atomicAdd(ap, v0);
            atomicAdd(ap + 1, v1);
        }
    }
    __syncthreads();

    for (int idx = t; idx < 32 * 64; idx += 256) {
        int nd = idx >> 6, fp = idx & 63;
        int n = n0 + nd;
        if (n < N) {
            float inv = invdeg[n];
            float a0 = acc[nd * 128 + 2 * fp] * inv;
            float a1 = acc[nd * 128 + 2 * fp + 1] * inv;
            unsigned out = (unsigned)f2bf(a0) | ((unsigned)f2bf(a1) << 16);
            *(unsigned*)(hN + ((size_t)n << 7) + 2 * fp) = out;
        }
    }
}

// ---------------- bf16 MFMA GEMM ----------------
// C[M,O] = A[M,K] @ W[O,K]^T (+bias, act).  A virtual concat at SPLIT (A1/A2 bf16).
// Block: 128 rows x O cols, 256 threads = 4 waves (2x2).
// OUTDT: 0 = fp32, 1 = bf16, 2 = fp16.

template<int K, int O, int SPLIT, int BIAS, int RELU, int OUTDT>
__global__ __launch_bounds__(256)
void k_mfma(int M,
            const u16* __restrict__ A1, int lda1,
            const u16* __restrict__ A2, int lda2,
            const u16* __restrict__ Wb,     // [O][K] dense bf16
            const float* __restrict__ bias,
            void* __restrict__ Cout, int ldc)
{
    constexpr int KP = K + 8;
    constexpr int NF = O / 32;   // N-frags per wave
    constexpr int WC = O / 2;    // cols per wave
    __shared__ __align__(16) u16 Wlds[O * KP];
    __shared__ __align__(16) u16 Atile[128 * 32];

    const int t = threadIdx.x;
    const int m0 = blockIdx.x * 128;
    const int w = t >> 6, l = t & 63;
    const int wm = w & 1, wn = w >> 1;
    const int lr = l & 15, lh = l >> 4;

    // stage W (L2-resident source)
    for (int idx = t; idx < O * (K / 8); idx += 256) {
        int row = idx / (K / 8), ch = idx % (K / 8);
        uint4 v = *(const uint4*)(Wb + (size_t)row * K + ch * 8);
        *(uint4*)(&Wlds[row * KP + ch * 8]) = v;
    }

    f32x4 acc[4][NF];
#pragma unroll
    for (int mi = 0; mi < 4; mi++)
#pragma unroll
        for (int ni = 0; ni < NF; ni++) acc[mi][ni] = (f32x4){0.f, 0.f, 0.f, 0.f};

    __syncthreads();

    for (int kt = 0; kt < K / 32; ++kt) {
        const int k0 = kt * 32;
        const u16* Asrc;
        int lda, kof;
        if (k0 < SPLIT) { Asrc = A1; lda = lda1; kof = k0; }
        else            { Asrc = A2; lda = lda2; kof = k0 - SPLIT; }
#pragma unroll
        for (int q = 0; q < 2; ++q) {
            int o = q * 4096 + t * 16;        // byte offset in Atile
            int row = o >> 6, cb = o & 63;
            int m = m0 + row;
            m = (m < M) ? m : (M - 1);        // clamp tail rows (results discarded on store)
            gload_lds16(Asrc + (size_t)m * lda + kof + (cb >> 1), (void*)(Atile + (o >> 1)));
        }
        __syncthreads();   // compiler drains vmcnt before barrier

        short8 a[4], b[NF];
#pragma unroll
        for (int mi = 0; mi < 4; mi++)
            a[mi] = *(const short8*)(Atile + (wm * 64 + mi * 16 + lr) * 32 + lh * 8);
#pragma unroll
        for (int ni = 0; ni < NF; ni++)
            b[ni] = *(const short8*)(Wlds + (size_t)(wn * WC + ni * 16 + lr) * KP + k0 + lh * 8);
#pragma unroll
        for (int mi = 0; mi < 4; mi++)
#pragma unroll
            for (int ni = 0; ni < NF; ni++)
                acc[mi][ni] = __builtin_amdgcn_mfma_f32_16x16x32_bf16(a[mi], b[ni], acc[mi][ni], 0, 0, 0);
        __syncthreads();   // before next stage overwrites Atile
    }

    // epilogue: D row = (lane>>4)*4 + reg, col = lane&15
    float bv[NF];
#pragma unroll
    for (int ni = 0; ni < NF; ni++)
        bv[ni] = BIAS ? bias[wn * WC + ni * 16 + lr] : 0.f;
#pragma unroll
    for (int mi = 0; mi < 4; mi++) {
#pragma unroll
        for (int i = 0; i < 4; i++) {
            int row = m0 + wm * 64 + mi * 16 + lh * 4 + i;
            if (row < M) {
#pragma unroll
                for (int ni = 0; ni < NF; ni++) {
                    float v = acc[mi][ni][i] + bv[ni];
                    if (RELU) v = fmaxf(v, 0.f);
                    int col = wn * WC + ni * 16 + lr;
                    if (OUTDT == 1)      ((u16*)Cout)[(size_t)row * ldc + col] = f2bf(v);
                    else if (OUTDT == 2) ((__half*)Cout)[(size_t)row * ldc + col] = __float2half(v);
                    else                 ((float*)Cout)[(size_t)row * ldc + col] = v;
                }
            }
        }
    }
}

// ---------------- launcher ----------------

extern "C" void kernel_launch(void* const* d_in, const int* in_sizes, int n_in,
                              void* d_out, int out_size, void* d_ws, size_t ws_size,
                              hipStream_t stream)
{
    const int N = in_sizes[0];
    const int E = in_sizes[1];
    const int* gate = (const int*)d_in[0];
    const int* src = (const int*)d_in[1];
    const int* dst = (const int*)d_in[2];
    const float* sidx = (const float*)d_in[3];
    const float* didx = (const float*)d_in[4];
    const float* rev = (const float*)d_in[5];
    const float* emb = (const float*)d_in[6];
    const float* w1[5] = {(const float*)d_in[7], (const float*)d_in[10], (const float*)d_in[13],
                          (const float*)d_in[16], (const float*)d_in[19]};
    const float* w2[5] = {(const float*)d_in[8], (const float*)d_in[11], (const float*)d_in[14],
                          (const float*)d_in[17], (const float*)d_in[20]};
    const float* b2[5] = {(const float*)d_in[9], (const float*)d_in[12], (const float*)d_in[15],
                          (const float*)d_in[18], (const float*)d_in[21]};

    char* ws = (char*)d_ws;
    size_t off = 0;
    auto alloc = [&](size_t bytes) {
        void* p = ws + off;
        off = (off + bytes + 255) & ~(size_t)255;
        return p;
    };
    u16* hb0 = (u16*)alloc((size_t)N * 128 * 2);
    u16* hb1 = (u16*)alloc((size_t)N * 128 * 2);
    u16* hN = (u16*)alloc((size_t)N * 128 * 2);
    u16* g = (u16*)alloc((size_t)N * 128 * 2);        // fp16
    int* cnt = (int*)alloc((size_t)N * 4);
    int* row_off = (int*)alloc((size_t)(N + 1) * 4);
    int* cursor = (int*)alloc((size_t)N * 4);
    int4* payload = (int4*)alloc((size_t)E * 16);
    int* edst = (int*)alloc((size_t)E * 4);
    int* partial = (int*)alloc(512 * 4);
    float* invd = (float*)alloc((size_t)N * 4);
    u16* w1b[5];
    u16* w2b[5];
    const int fis[5] = {64, 128, 128, 128, 128};
    for (int i = 0; i < 5; i++) w1b[i] = (u16*)alloc((size_t)128 * fis[i] * 2);
    for (int i = 0; i < 5; i++) {
        int fo = (i == 4) ? 64 : 128;
        w2b[i] = (u16*)alloc((size_t)fo * (fis[i] + 128) * 2);
    }

    // weight conversions (one launch)
    WDesc wd;
    for (int i = 0; i < 5; i++) {
        wd.src[i] = w1[i]; wd.dst[i] = w1b[i];
        wd.scols[i] = fis[i] + 3; wd.dcols[i] = fis[i]; wd.n[i] = 128 * fis[i];
        int fo = (i == 4) ? 64 : 128;
        wd.src[5 + i] = w2[i]; wd.dst[5 + i] = w2b[i];
        wd.scols[5 + i] = fis[i] + 128; wd.dcols[5 + i] = fis[i] + 128;
        wd.n[5 + i] = fo * (fis[i] + 128);
    }
    k_wconv<<<dim3(128, 10), dim3(256), 0, stream>>>(wd);

    hipMemsetAsync(cnt, 0, (size_t)N * 4, stream);
    k_count<<<dim3((E + 255) / 256), dim3(256), 0, stream>>>(dst, cnt, E);
    const int nb = (N + 255) / 256;
    k_scan1<<<dim3(nb), dim3(256), 0, stream>>>(cnt, partial, N);
    k_scan2<<<dim3(1), dim3(512), 0, stream>>>(partial, nb);
    k_scan3<<<dim3(nb), dim3(256), 0, stream>>>(cnt, partial, row_off, cursor, invd, N, E);
    k_scatter<<<dim3((E + 255) / 256), dim3(256), 0, stream>>>(dst, src, sidx, didx, rev, cursor, payload, edst, E);
    k_emb<<<dim3((N * 64 + 255) / 256), dim3(256), 0, stream>>>(gate, emb, hb0, N);

    u16* hcur = hb0;
    u16* hnxt = hb1;
    const int gg = (N + 127) / 128;
    const int eg = (N + 31) / 32;   // 32 nodes per block (edge-slab)

    // ---- layer 1 (fi=64) ----
    k_mfma<64, 128, 64, 0, 0, 2><<<dim3(gg), dim3(256), 0, stream>>>(
        N, hcur, 64, (const u16*)nullptr, 0, w1b[0], (const float*)nullptr, g, 128);
    k_edge<<<dim3(eg), dim3(256), 0, stream>>>(N, 64, row_off, payload, edst, g, w1[0], invd, hN);
    k_mfma<192, 128, 64, 1, 1, 1><<<dim3(gg), dim3(256), 0, stream>>>(
        N, hcur, 64, hN, 128, w2b[0], b2[0], hnxt, 128);
    hcur = hb1; hnxt = hb0;

    // ---- layers 2..4 (fi=128) ----
    for (int l = 1; l < 4; ++l) {
        k_mfma<128, 128, 128, 0, 0, 2><<<dim3(gg), dim3(256), 0, stream>>>(
            N, hcur, 128, (const u16*)nullptr, 0, w1b[l], (const float*)nullptr, g, 128);
        k_edge<<<dim3(eg), dim3(256), 0, stream>>>(N, 128, row_off, payload, edst, g, w1[l], invd, hN);
        k_mfma<256, 128, 128, 1, 1, 1><<<dim3(gg), dim3(256), 0, stream>>>(
            N, hcur, 128, hN, 128, w2b[l], b2[l], hnxt, 128);
        u16* tmp = hcur; hcur = hnxt; hnxt = tmp;
    }

    // ---- layer 5 (fi=128, out 64 fp32, no relu) ----
    k_mfma<128, 128, 128, 0, 0, 2><<<dim3(gg), dim3(256), 0, stream>>>(
        N, hcur, 128, (const u16*)nullptr, 0, w1b[4], (const float*)nullptr, g, 128);
    k_edge<<<dim3(eg), dim3(256), 0, stream>>>(N, 128, row_off, payload, edst, g, w1[4], invd, hN);
    k_mfma<256, 64, 128, 1, 0, 0><<<dim3(gg), dim3(256), 0, stream>>>(
        N, hcur, 128, hN, 128, w2b[4], b2[4], (float*)d_out, 64);
}

// Round 6
// 526.688 us; speedup vs baseline: 3.1884x; 3.1884x over previous
//
#include <hip/hip_runtime.h>
#include <hip/hip_fp16.h>

typedef __attribute__((ext_vector_type(8))) short short8;
typedef __attribute__((ext_vector_type(4))) float f32x4;
typedef unsigned short u16;

__device__ __forceinline__ u16 f2bf(float f) {
    unsigned u = __float_as_uint(f);
    unsigned r = ((u >> 16) & 1) + 0x7FFFu;
    return (u16)((u + r) >> 16);
}

__device__ __forceinline__ void gload_lds16(const void* g, void* l) {
    __builtin_amdgcn_global_load_lds((const __attribute__((address_space(1))) unsigned int*)g,
                                     (__attribute__((address_space(3))) unsigned int*)l,
                                     16, 0, 0);
}

// ---------------- CSR build kernels ----------------

__global__ void k_count(const int* __restrict__ dst, int* __restrict__ cnt, int E) {
    int i = blockIdx.x * 256 + threadIdx.x;
    if (i < E) atomicAdd(&cnt[dst[i]], 1);
}

__global__ void k_scan1(const int* __restrict__ cnt, int* __restrict__ partial, int N) {
    __shared__ int sm[256];
    int idx = blockIdx.x * 256 + threadIdx.x;
    sm[threadIdx.x] = (idx < N) ? cnt[idx] : 0;
    __syncthreads();
    for (int s = 128; s > 0; s >>= 1) {
        if (threadIdx.x < s) sm[threadIdx.x] += sm[threadIdx.x + s];
        __syncthreads();
    }
    if (threadIdx.x == 0) partial[blockIdx.x] = sm[0];
}

__global__ void k_scan2(int* __restrict__ partial, int nb) {
    __shared__ int sm[512];
    int t = threadIdx.x;
    sm[t] = (t < nb) ? partial[t] : 0;
    __syncthreads();
    for (int off = 1; off < 512; off <<= 1) {
        int v = (t >= off) ? sm[t - off] : 0;
        __syncthreads();
        sm[t] += v;
        __syncthreads();
    }
    if (t < nb) partial[t] = (t == 0) ? 0 : sm[t - 1];  // exclusive
}

__global__ void k_scan3(const int* __restrict__ cnt, const int* __restrict__ partial,
                        int* __restrict__ row_off, int* __restrict__ cursor,
                        float* __restrict__ invdeg, int N, int E) {
    __shared__ int sm[256];
    int idx = blockIdx.x * 256 + threadIdx.x;
    int v = (idx < N) ? cnt[idx] : 0;
    sm[threadIdx.x] = v;
    __syncthreads();
    for (int off = 1; off < 256; off <<= 1) {
        int u = (threadIdx.x >= off) ? sm[threadIdx.x - off] : 0;
        __syncthreads();
        sm[threadIdx.x] += u;
        __syncthreads();
    }
    if (idx < N) {
        int excl = partial[blockIdx.x] + sm[threadIdx.x] - v;
        row_off[idx] = excl;
        cursor[idx] = excl;
        invdeg[idx] = 1.0f / (float)((v > 1) ? v : 1);
    }
    if (idx == 0) row_off[N] = E;
}

// scatter edge payload directly into CSR slots: {src, si, di, rv}
__global__ void k_scatter(const int* __restrict__ dst, const int* __restrict__ src,
                          const float* __restrict__ sidx, const float* __restrict__ didx,
                          const float* __restrict__ rev,
                          int* __restrict__ cursor, int4* __restrict__ payload, int E) {
    int i = blockIdx.x * 256 + threadIdx.x;
    if (i < E) {
        int p = atomicAdd(&cursor[dst[i]], 1);
        int4 v;
        v.x = src[i];
        v.y = __float_as_int(sidx[i]);
        v.z = __float_as_int(didx[i]);
        v.w = __float_as_int(rev[i]);
        payload[p] = v;
    }
}

// ---------------- embedding gather (bf16 out) ----------------

__global__ void k_emb(const int* __restrict__ gt, const float* __restrict__ emb,
                      u16* __restrict__ h0, int N) {
    int i = blockIdx.x * 256 + threadIdx.x;
    if (i < N * 64) {
        int n = i >> 6, f = i & 63;
        h0[i] = f2bf(emb[(gt[n] << 6) | f]);
    }
}

// ---------------- weight fp32 -> bf16 dense conversion ----------------

struct WDesc {
    const float* src[10];
    u16* dst[10];
    int scols[10];
    int dcols[10];
    int n[10];
};

__global__ void k_wconv(WDesc d) {
    int seg = blockIdx.y;
    int idx = blockIdx.x * 256 + threadIdx.x;
    if (idx < d.n[seg]) {
        int dc = d.dcols[seg];
        int r = idx / dc, c = idx % dc;
        d.dst[seg][idx] = f2bf(d.src[seg][r * d.scols[seg] + c]);
    }
}

// ---------------- edge aggregation: wave per node, 2 edge-groups x 32 lanes ----------------
// lane = 32*eg + fl; lane covers feats 4*fl..4*fl+3 (8B fp16 gather).
// eg 0/1 process even/odd edges concurrently, each depth-2 pipelined.
// Final: shfl_xor(32) reduce, lanes 0-31 store.

__global__ __launch_bounds__(256)
void k_edge(int N, int fi,
            const int* __restrict__ row_off, const int4* __restrict__ payload,
            const u16* __restrict__ g,        // [N,128] fp16
            const float* __restrict__ W1,     // [128, fi+3] fp32 original
            const float* __restrict__ invdeg,
            u16* __restrict__ hN)             // [N,128] bf16
{
    const int lane = threadIdx.x & 63;
    const int fl = lane & 31;
    const int eg = lane >> 5;
    const int n = (blockIdx.x * blockDim.x + threadIdx.x) >> 6;
    if (n >= N) return;

    const int ldw1 = fi + 3;
    float wgt[4][3];
#pragma unroll
    for (int r = 0; r < 4; r++) {
        const float* wr = W1 + (size_t)(4 * fl + r) * ldw1 + fi;
        wgt[r][0] = wr[0];
        wgt[r][1] = wr[1];
        wgt[r][2] = wr[2];
    }

    const int beg = row_off[n];
    const int end = row_off[n + 1];
    float acc[4] = {0.f, 0.f, 0.f, 0.f};

    int p = beg + eg;
    int4 pl;
    uint2 gv;
    if (p < end) {
        pl = payload[p];
        gv = *(const uint2*)(g + ((size_t)pl.x << 7) + (fl << 2));
    }
    while (p < end) {
        const int pn = p + 2;
        int4 plN;
        uint2 gvN;
        if (pn < end) {
            plN = payload[pn];
            gvN = *(const uint2*)(g + ((size_t)plN.x << 7) + (fl << 2));
        }
        const float si = __int_as_float(pl.y);
        const float di = __int_as_float(pl.z);
        const float rv = __int_as_float(pl.w);
        const float2 f01 = __half22float2(*(const __half2*)&gv.x);
        const float2 f23 = __half22float2(*(const __half2*)&gv.y);
        float v0 = f01.x + wgt[0][0] * si + wgt[0][1] * di + wgt[0][2] * rv;
        float v1 = f01.y + wgt[1][0] * si + wgt[1][1] * di + wgt[1][2] * rv;
        float v2 = f23.x + wgt[2][0] * si + wgt[2][1] * di + wgt[2][2] * rv;
        float v3 = f23.y + wgt[3][0] * si + wgt[3][1] * di + wgt[3][2] * rv;
        acc[0] += (v0 > 0.f) ? v0 : 0.01f * v0;
        acc[1] += (v1 > 0.f) ? v1 : 0.01f * v1;
        acc[2] += (v2 > 0.f) ? v2 : 0.01f * v2;
        acc[3] += (v3 > 0.f) ? v3 : 0.01f * v3;
        p = pn;
        pl = plN;
        gv = gvN;
    }

    // combine the two edge groups
#pragma unroll
    for (int r = 0; r < 4; r++) acc[r] += __shfl_xor(acc[r], 32, 64);

    if (eg == 0) {
        const float inv = invdeg[n];
        unsigned o0 = (unsigned)f2bf(acc[0] * inv) | ((unsigned)f2bf(acc[1] * inv) << 16);
        unsigned o1 = (unsigned)f2bf(acc[2] * inv) | ((unsigned)f2bf(acc[3] * inv) << 16);
        uint2 out = make_uint2(o0, o1);
        *(uint2*)(hN + ((size_t)n << 7) + (fl << 2)) = out;
    }
}

// ---------------- bf16 MFMA GEMM ----------------
// C[M,O] = A[M,K] @ W[O,K]^T (+bias, act).  A virtual concat at SPLIT (A1/A2 bf16).
// Block: 128 rows x O cols, 256 threads = 4 waves (2x2).
// OUTDT: 0 = fp32, 1 = bf16, 2 = fp16.

template<int K, int O, int SPLIT, int BIAS, int RELU, int OUTDT>
__global__ __launch_bounds__(256)
void k_mfma(int M,
            const u16* __restrict__ A1, int lda1,
            const u16* __restrict__ A2, int lda2,
            const u16* __restrict__ Wb,     // [O][K] dense bf16
            const float* __restrict__ bias,
            void* __restrict__ Cout, int ldc)
{
    constexpr int KP = K + 8;
    constexpr int NF = O / 32;   // N-frags per wave
    constexpr int WC = O / 2;    // cols per wave
    __shared__ __align__(16) u16 Wlds[O * KP];
    __shared__ __align__(16) u16 Atile[128 * 32];

    const int t = threadIdx.x;
    const int m0 = blockIdx.x * 128;
    const int w = t >> 6, l = t & 63;
    const int wm = w & 1, wn = w >> 1;
    const int lr = l & 15, lh = l >> 4;

    // stage W (L2-resident source)
    for (int idx = t; idx < O * (K / 8); idx += 256) {
        int row = idx / (K / 8), ch = idx % (K / 8);
        uint4 v = *(const uint4*)(Wb + (size_t)row * K + ch * 8);
        *(uint4*)(&Wlds[row * KP + ch * 8]) = v;
    }

    f32x4 acc[4][NF];
#pragma unroll
    for (int mi = 0; mi < 4; mi++)
#pragma unroll
        for (int ni = 0; ni < NF; ni++) acc[mi][ni] = (f32x4){0.f, 0.f, 0.f, 0.f};

    __syncthreads();

    for (int kt = 0; kt < K / 32; ++kt) {
        const int k0 = kt * 32;
        const u16* Asrc;
        int lda, kof;
        if (k0 < SPLIT) { Asrc = A1; lda = lda1; kof = k0; }
        else            { Asrc = A2; lda = lda2; kof = k0 - SPLIT; }
#pragma unroll
        for (int q = 0; q < 2; ++q) {
            int o = q * 4096 + t * 16;        // byte offset in Atile
            int row = o >> 6, cb = o & 63;
            int m = m0 + row;
            m = (m < M) ? m : (M - 1);        // clamp tail rows (results discarded on store)
            gload_lds16(Asrc + (size_t)m * lda + kof + (cb >> 1), (void*)(Atile + (o >> 1)));
        }
        __syncthreads();   // compiler drains vmcnt before barrier

        short8 a[4], b[NF];
#pragma unroll
        for (int mi = 0; mi < 4; mi++)
            a[mi] = *(const short8*)(Atile + (wm * 64 + mi * 16 + lr) * 32 + lh * 8);
#pragma unroll
        for (int ni = 0; ni < NF; ni++)
            b[ni] = *(const short8*)(Wlds + (size_t)(wn * WC + ni * 16 + lr) * KP + k0 + lh * 8);
#pragma unroll
        for (int mi = 0; mi < 4; mi++)
#pragma unroll
            for (int ni = 0; ni < NF; ni++)
                acc[mi][ni] = __builtin_amdgcn_mfma_f32_16x16x32_bf16(a[mi], b[ni], acc[mi][ni], 0, 0, 0);
        __syncthreads();   // before next stage overwrites Atile
    }

    // epilogue: D row = (lane>>4)*4 + reg, col = lane&15
    float bv[NF];
#pragma unroll
    for (int ni = 0; ni < NF; ni++)
        bv[ni] = BIAS ? bias[wn * WC + ni * 16 + lr] : 0.f;
#pragma unroll
    for (int mi = 0; mi < 4; mi++) {
#pragma unroll
        for (int i = 0; i < 4; i++) {
            int row = m0 + wm * 64 + mi * 16 + lh * 4 + i;
            if (row < M) {
#pragma unroll
                for (int ni = 0; ni < NF; ni++) {
                    float v = acc[mi][ni][i] + bv[ni];
                    if (RELU) v = fmaxf(v, 0.f);
                    int col = wn * WC + ni * 16 + lr;
                    if (OUTDT == 1)      ((u16*)Cout)[(size_t)row * ldc + col] = f2bf(v);
                    else if (OUTDT == 2) ((__half*)Cout)[(size_t)row * ldc + col] = __float2half(v);
                    else                 ((float*)Cout)[(size_t)row * ldc + col] = v;
                }
            }
        }
    }
}

// ---------------- launcher ----------------

extern "C" void kernel_launch(void* const* d_in, const int* in_sizes, int n_in,
                              void* d_out, int out_size, void* d_ws, size_t ws_size,
                              hipStream_t stream)
{
    const int N = in_sizes[0];
    const int E = in_sizes[1];
    const int* gate = (const int*)d_in[0];
    const int* src = (const int*)d_in[1];
    const int* dst = (const int*)d_in[2];
    const float* sidx = (const float*)d_in[3];
    const float* didx = (const float*)d_in[4];
    const float* rev = (const float*)d_in[5];
    const float* emb = (const float*)d_in[6];
    const float* w1[5] = {(const float*)d_in[7], (const float*)d_in[10], (const float*)d_in[13],
                          (const float*)d_in[16], (const float*)d_in[19]};
    const float* w2[5] = {(const float*)d_in[8], (const float*)d_in[11], (const float*)d_in[14],
                          (const float*)d_in[17], (const float*)d_in[20]};
    const float* b2[5] = {(const float*)d_in[9], (const float*)d_in[12], (const float*)d_in[15],
                          (const float*)d_in[18], (const float*)d_in[21]};

    char* ws = (char*)d_ws;
    size_t off = 0;
    auto alloc = [&](size_t bytes) {
        void* p = ws + off;
        off = (off + bytes + 255) & ~(size_t)255;
        return p;
    };
    u16* hb0 = (u16*)alloc((size_t)N * 128 * 2);
    u16* hb1 = (u16*)alloc((size_t)N * 128 * 2);
    u16* hN = (u16*)alloc((size_t)N * 128 * 2);
    u16* g = (u16*)alloc((size_t)N * 128 * 2);        // fp16
    int* cnt = (int*)alloc((size_t)N * 4);
    int* row_off = (int*)alloc((size_t)(N + 1) * 4);
    int* cursor = (int*)alloc((size_t)N * 4);
    int4* payload = (int4*)alloc((size_t)E * 16);
    int* partial = (int*)alloc(512 * 4);
    float* invd = (float*)alloc((size_t)N * 4);
    u16* w1b[5];
    u16* w2b[5];
    const int fis[5] = {64, 128, 128, 128, 128};
    for (int i = 0; i < 5; i++) w1b[i] = (u16*)alloc((size_t)128 * fis[i] * 2);
    for (int i = 0; i < 5; i++) {
        int fo = (i == 4) ? 64 : 128;
        w2b[i] = (u16*)alloc((size_t)fo * (fis[i] + 128) * 2);
    }

    // weight conversions (one launch)
    WDesc wd;
    for (int i = 0; i < 5; i++) {
        wd.src[i] = w1[i]; wd.dst[i] = w1b[i];
        wd.scols[i] = fis[i] + 3; wd.dcols[i] = fis[i]; wd.n[i] = 128 * fis[i];
        int fo = (i == 4) ? 64 : 128;
        wd.src[5 + i] = w2[i]; wd.dst[5 + i] = w2b[i];
        wd.scols[5 + i] = fis[i] + 128; wd.dcols[5 + i] = fis[i] + 128;
        wd.n[5 + i] = fo * (fis[i] + 128);
    }
    k_wconv<<<dim3(128, 10), dim3(256), 0, stream>>>(wd);

    hipMemsetAsync(cnt, 0, (size_t)N * 4, stream);
    k_count<<<dim3((E + 255) / 256), dim3(256), 0, stream>>>(dst, cnt, E);
    const int nb = (N + 255) / 256;
    k_scan1<<<dim3(nb), dim3(256), 0, stream>>>(cnt, partial, N);
    k_scan2<<<dim3(1), dim3(512), 0, stream>>>(partial, nb);
    k_scan3<<<dim3(nb), dim3(256), 0, stream>>>(cnt, partial, row_off, cursor, invd, N, E);
    k_scatter<<<dim3((E + 255) / 256), dim3(256), 0, stream>>>(dst, src, sidx, didx, rev, cursor, payload, E);
    k_emb<<<dim3((N * 64 + 255) / 256), dim3(256), 0, stream>>>(gate, emb, hb0, N);

    u16* hcur = hb0;
    u16* hnxt = hb1;
    const int gg = (N + 127) / 128;
    const int eg = (N + 3) / 4;   // 4 waves/block, 1 node/wave

    // ---- layer 1 (fi=64) ----
    k_mfma<64, 128, 64, 0, 0, 2><<<dim3(gg), dim3(256), 0, stream>>>(
        N, hcur, 64, (const u16*)nullptr, 0, w1b[0], (const float*)nullptr, g, 128);
    k_edge<<<dim3(eg), dim3(256), 0, stream>>>(N, 64, row_off, payload, g, w1[0], invd, hN);
    k_mfma<192, 128, 64, 1, 1, 1><<<dim3(gg), dim3(256), 0, stream>>>(
        N, hcur, 64, hN, 128, w2b[0], b2[0], hnxt, 128);
    hcur = hb1; hnxt = hb0;

    // ---- layers 2..4 (fi=128) ----
    for (int l = 1; l < 4; ++l) {
        k_mfma<128, 128, 128, 0, 0, 2><<<dim3(gg), dim3(256), 0, stream>>>(
            N, hcur, 128, (const u16*)nullptr, 0, w1b[l], (const float*)nullptr, g, 128);
        k_edge<<<dim3(eg), dim3(256), 0, stream>>>(N, 128, row_off, payload, g, w1[l], invd, hN);
        k_mfma<256, 128, 128, 1, 1, 1><<<dim3(gg), dim3(256), 0, stream>>>(
            N, hcur, 128, hN, 128, w2b[l], b2[l], hnxt, 128);
        u16* tmp = hcur; hcur = hnxt; hnxt = tmp;
    }

    // ---- layer 5 (fi=128, out 64 fp32, no relu) ----
    k_mfma<128, 128, 128, 0, 0, 2><<<dim3(gg), dim3(256), 0, stream>>>(
        N, hcur, 128, (const u16*)nullptr, 0, w1b[4], (const float*)nullptr, g, 128);
    k_edge<<<dim3(eg), dim3(256), 0, stream>>>(N, 128, row_off, payload, g, w1[4], invd, hN);
    k_mfma<256, 64, 128, 1, 0, 0><<<dim3(gg), dim3(256), 0, stream>>>(
        N, hcur, 128, hN, 128, w2b[4], b2[4], (float*)d_out, 64);
}

// Round 7
// 493.049 us; speedup vs baseline: 3.4060x; 1.0682x over previous
//
#include <hip/hip_runtime.h>
#include <hip/hip_fp16.h>

typedef __attribute__((ext_vector_type(8))) short short8;
typedef __attribute__((ext_vector_type(4))) float f32x4;
typedef unsigned short u16;

__device__ __forceinline__ u16 f2bf(float f) {
    unsigned u = __float_as_uint(f);
    unsigned r = ((u >> 16) & 1) + 0x7FFFu;
    return (u16)((u + r) >> 16);
}

__device__ __forceinline__ void gload_lds16(const void* g, void* l) {
    __builtin_amdgcn_global_load_lds((const __attribute__((address_space(1))) unsigned int*)g,
                                     (__attribute__((address_space(3))) unsigned int*)l,
                                     16, 0, 0);
}

// ---------------- CSR build kernels ----------------

__global__ void k_count(const int* __restrict__ dst, int* __restrict__ cnt, int E) {
    int i = blockIdx.x * 256 + threadIdx.x;
    if (i < E) atomicAdd(&cnt[dst[i]], 1);
}

__global__ void k_scan1(const int* __restrict__ cnt, int* __restrict__ partial, int N) {
    __shared__ int sm[256];
    int idx = blockIdx.x * 256 + threadIdx.x;
    sm[threadIdx.x] = (idx < N) ? cnt[idx] : 0;
    __syncthreads();
    for (int s = 128; s > 0; s >>= 1) {
        if (threadIdx.x < s) sm[threadIdx.x] += sm[threadIdx.x + s];
        __syncthreads();
    }
    if (threadIdx.x == 0) partial[blockIdx.x] = sm[0];
}

__global__ void k_scan2(int* __restrict__ partial, int nb) {
    __shared__ int sm[512];
    int t = threadIdx.x;
    sm[t] = (t < nb) ? partial[t] : 0;
    __syncthreads();
    for (int off = 1; off < 512; off <<= 1) {
        int v = (t >= off) ? sm[t - off] : 0;
        __syncthreads();
        sm[t] += v;
        __syncthreads();
    }
    if (t < nb) partial[t] = (t == 0) ? 0 : sm[t - 1];  // exclusive
}

__global__ void k_scan3(const int* __restrict__ cnt, const int* __restrict__ partial,
                        int* __restrict__ row_off, int* __restrict__ cursor,
                        float* __restrict__ invdeg, int N, int E) {
    __shared__ int sm[256];
    int idx = blockIdx.x * 256 + threadIdx.x;
    int v = (idx < N) ? cnt[idx] : 0;
    sm[threadIdx.x] = v;
    __syncthreads();
    for (int off = 1; off < 256; off <<= 1) {
        int u = (threadIdx.x >= off) ? sm[threadIdx.x - off] : 0;
        __syncthreads();
        sm[threadIdx.x] += u;
        __syncthreads();
    }
    if (idx < N) {
        int excl = partial[blockIdx.x] + sm[threadIdx.x] - v;
        row_off[idx] = excl;
        cursor[idx] = excl;
        invdeg[idx] = 1.0f / (float)((v > 1) ? v : 1);
    }
    if (idx == 0) row_off[N] = E;
}

// scatter edge payload directly into CSR slots: {src, si, di, rv}
__global__ void k_scatter(const int* __restrict__ dst, const int* __restrict__ src,
                          const float* __restrict__ sidx, const float* __restrict__ didx,
                          const float* __restrict__ rev,
                          int* __restrict__ cursor, int4* __restrict__ payload, int E) {
    int i = blockIdx.x * 256 + threadIdx.x;
    if (i < E) {
        int p = atomicAdd(&cursor[dst[i]], 1);
        int4 v;
        v.x = src[i];
        v.y = __float_as_int(sidx[i]);
        v.z = __float_as_int(didx[i]);
        v.w = __float_as_int(rev[i]);
        payload[p] = v;
    }
}

// ---------------- embedding gather (bf16 out) ----------------

__global__ void k_emb(const int* __restrict__ gt, const float* __restrict__ emb,
                      u16* __restrict__ h0, int N) {
    int i = blockIdx.x * 256 + threadIdx.x;
    if (i < N * 64) {
        int n = i >> 6, f = i & 63;
        h0[i] = f2bf(emb[(gt[n] << 6) | f]);
    }
}

// ---------------- weight fp32 -> bf16 dense conversion ----------------

struct WDesc {
    const float* src[10];
    u16* dst[10];
    int scols[10];
    int dcols[10];
    int n[10];
};

__global__ void k_wconv(WDesc d) {
    int seg = blockIdx.y;
    int idx = blockIdx.x * 256 + threadIdx.x;
    if (idx < d.n[seg]) {
        int dc = d.dcols[seg];
        int r = idx / dc, c = idx % dc;
        d.dst[seg][idx] = f2bf(d.src[seg][r * d.scols[seg] + c]);
    }
}

// edge-weight columns of W1, transposed dense: W1e[c][r] = W1[r][fi+c], c<3, r<128
struct EDesc {
    const float* src[5];
    float* dst[5];
    int ldw[5];
    int fi[5];
};

__global__ void k_wedge(EDesc d) {
    int l = blockIdx.x;
    int i = threadIdx.x;
    if (i < 384) {
        int c = i >> 7, r = i & 127;
        d.dst[l][(c << 7) + r] = d.src[l][(size_t)r * d.ldw[l] + d.fi[l] + c];
    }
}

// ---------------- edge aggregation: wave per node, 4 edge-groups x 16 lanes ----------------
// lane = 16*eg + fl; lane covers feats 8*fl..8*fl+7 (16B fp16 gather).
// One dwordx4 gather instruction fetches 4 edges' rows (one per group).
// Payload prefetched one iteration ahead. Reduce: shfl_xor 16/32, lanes 0-15 store uint4.

__global__ __launch_bounds__(256)
void k_edge(int N,
            const int* __restrict__ row_off, const int4* __restrict__ payload,
            const u16* __restrict__ g,        // [N,128] fp16
            const float* __restrict__ W1e,    // [3][128] fp32
            const float* __restrict__ invdeg,
            u16* __restrict__ hN)             // [N,128] bf16
{
    const int lane = threadIdx.x & 63;
    const int fl = lane & 15;
    const int eg = lane >> 4;
    const int n = (blockIdx.x * blockDim.x + threadIdx.x) >> 6;
    if (n >= N) return;

    const int beg = row_off[n];
    const int end = row_off[n + 1];

    int p = beg + eg;
    int4 pl;
    if (p < end) pl = payload[p];

    // coalesced per-lane weight rows (L2-resident, 6 x float4)
    const float4 wa0 = *(const float4*)&W1e[(fl << 3)];
    const float4 wa1 = *(const float4*)&W1e[(fl << 3) + 4];
    const float4 wb0 = *(const float4*)&W1e[128 + (fl << 3)];
    const float4 wb1 = *(const float4*)&W1e[128 + (fl << 3) + 4];
    const float4 wc0 = *(const float4*)&W1e[256 + (fl << 3)];
    const float4 wc1 = *(const float4*)&W1e[256 + (fl << 3) + 4];

    float acc[8] = {0.f, 0.f, 0.f, 0.f, 0.f, 0.f, 0.f, 0.f};

    while (p < end) {
        const int pn = p + 4;
        int4 plN;
        if (pn < end) plN = payload[pn];
        const uint4 gv = *(const uint4*)(g + ((size_t)pl.x << 7) + (fl << 3));
        const float si = __int_as_float(pl.y);
        const float di = __int_as_float(pl.z);
        const float rv = __int_as_float(pl.w);
        const float2 f0 = __half22float2(*(const __half2*)&gv.x);
        const float2 f1 = __half22float2(*(const __half2*)&gv.y);
        const float2 f2 = __half22float2(*(const __half2*)&gv.z);
        const float2 f3 = __half22float2(*(const __half2*)&gv.w);
        float v[8];
        v[0] = f0.x + wa0.x * si + wb0.x * di + wc0.x * rv;
        v[1] = f0.y + wa0.y * si + wb0.y * di + wc0.y * rv;
        v[2] = f1.x + wa0.z * si + wb0.z * di + wc0.z * rv;
        v[3] = f1.y + wa0.w * si + wb0.w * di + wc0.w * rv;
        v[4] = f2.x + wa1.x * si + wb1.x * di + wc1.x * rv;
        v[5] = f2.y + wa1.y * si + wb1.y * di + wc1.y * rv;
        v[6] = f3.x + wa1.z * si + wb1.z * di + wc1.z * rv;
        v[7] = f3.y + wa1.w * si + wb1.w * di + wc1.w * rv;
#pragma unroll
        for (int r = 0; r < 8; r++)
            acc[r] += (v[r] > 0.f) ? v[r] : 0.01f * v[r];
        p = pn;
        pl = plN;
    }

    // combine the 4 edge groups
#pragma unroll
    for (int r = 0; r < 8; r++) {
        acc[r] += __shfl_xor(acc[r], 16, 64);
        acc[r] += __shfl_xor(acc[r], 32, 64);
    }

    if (eg == 0) {
        const float inv = invdeg[n];
        unsigned q0 = (unsigned)f2bf(acc[0] * inv) | ((unsigned)f2bf(acc[1] * inv) << 16);
        unsigned q1 = (unsigned)f2bf(acc[2] * inv) | ((unsigned)f2bf(acc[3] * inv) << 16);
        unsigned q2 = (unsigned)f2bf(acc[4] * inv) | ((unsigned)f2bf(acc[5] * inv) << 16);
        unsigned q3 = (unsigned)f2bf(acc[6] * inv) | ((unsigned)f2bf(acc[7] * inv) << 16);
        uint4 out = make_uint4(q0, q1, q2, q3);
        *(uint4*)(hN + ((size_t)n << 7) + (fl << 3)) = out;
    }
}

// ---------------- bf16 MFMA GEMM ----------------
// C[M,O] = A[M,K] @ W[O,K]^T (+bias, act).  A virtual concat at SPLIT (A1/A2 bf16).
// Block: 128 rows x O cols, 256 threads = 4 waves (2x2).
// OUTDT: 0 = fp32, 1 = bf16, 2 = fp16.

template<int K, int O, int SPLIT, int BIAS, int RELU, int OUTDT>
__global__ __launch_bounds__(256)
void k_mfma(int M,
            const u16* __restrict__ A1, int lda1,
            const u16* __restrict__ A2, int lda2,
            const u16* __restrict__ Wb,     // [O][K] dense bf16
            const float* __restrict__ bias,
            void* __restrict__ Cout, int ldc)
{
    constexpr int KP = K + 8;
    constexpr int NF = O / 32;   // N-frags per wave
    constexpr int WC = O / 2;    // cols per wave
    __shared__ __align__(16) u16 Wlds[O * KP];
    __shared__ __align__(16) u16 Atile[128 * 32];

    const int t = threadIdx.x;
    const int m0 = blockIdx.x * 128;
    const int w = t >> 6, l = t & 63;
    const int wm = w & 1, wn = w >> 1;
    const int lr = l & 15, lh = l >> 4;

    // stage W (L2-resident source)
    for (int idx = t; idx < O * (K / 8); idx += 256) {
        int row = idx / (K / 8), ch = idx % (K / 8);
        uint4 v = *(const uint4*)(Wb + (size_t)row * K + ch * 8);
        *(uint4*)(&Wlds[row * KP + ch * 8]) = v;
    }

    f32x4 acc[4][NF];
#pragma unroll
    for (int mi = 0; mi < 4; mi++)
#pragma unroll
        for (int ni = 0; ni < NF; ni++) acc[mi][ni] = (f32x4){0.f, 0.f, 0.f, 0.f};

    __syncthreads();

    for (int kt = 0; kt < K / 32; ++kt) {
        const int k0 = kt * 32;
        const u16* Asrc;
        int lda, kof;
        if (k0 < SPLIT) { Asrc = A1; lda = lda1; kof = k0; }
        else            { Asrc = A2; lda = lda2; kof = k0 - SPLIT; }
#pragma unroll
        for (int q = 0; q < 2; ++q) {
            int o = q * 4096 + t * 16;        // byte offset in Atile
            int row = o >> 6, cb = o & 63;
            int m = m0 + row;
            m = (m < M) ? m : (M - 1);        // clamp tail rows (results discarded on store)
            gload_lds16(Asrc + (size_t)m * lda + kof + (cb >> 1), (void*)(Atile + (o >> 1)));
        }
        __syncthreads();   // compiler drains vmcnt before barrier

        short8 a[4], b[NF];
#pragma unroll
        for (int mi = 0; mi < 4; mi++)
            a[mi] = *(const short8*)(Atile + (wm * 64 + mi * 16 + lr) * 32 + lh * 8);
#pragma unroll
        for (int ni = 0; ni < NF; ni++)
            b[ni] = *(const short8*)(Wlds + (size_t)(wn * WC + ni * 16 + lr) * KP + k0 + lh * 8);
#pragma unroll
        for (int mi = 0; mi < 4; mi++)
#pragma unroll
            for (int ni = 0; ni < NF; ni++)
                acc[mi][ni] = __builtin_amdgcn_mfma_f32_16x16x32_bf16(a[mi], b[ni], acc[mi][ni], 0, 0, 0);
        __syncthreads();   // before next stage overwrites Atile
    }

    // epilogue: D row = (lane>>4)*4 + reg, col = lane&15
    float bv[NF];
#pragma unroll
    for (int ni = 0; ni < NF; ni++)
        bv[ni] = BIAS ? bias[wn * WC + ni * 16 + lr] : 0.f;
#pragma unroll
    for (int mi = 0; mi < 4; mi++) {
#pragma unroll
        for (int i = 0; i < 4; i++) {
            int row = m0 + wm * 64 + mi * 16 + lh * 4 + i;
            if (row < M) {
#pragma unroll
                for (int ni = 0; ni < NF; ni++) {
                    float v = acc[mi][ni][i] + bv[ni];
                    if (RELU) v = fmaxf(v, 0.f);
                    int col = wn * WC + ni * 16 + lr;
                    if (OUTDT == 1)      ((u16*)Cout)[(size_t)row * ldc + col] = f2bf(v);
                    else if (OUTDT == 2) ((__half*)Cout)[(size_t)row * ldc + col] = __float2half(v);
                    else                 ((float*)Cout)[(size_t)row * ldc + col] = v;
                }
            }
        }
    }
}

// ---------------- launcher ----------------

extern "C" void kernel_launch(void* const* d_in, const int* in_sizes, int n_in,
                              void* d_out, int out_size, void* d_ws, size_t ws_size,
                              hipStream_t stream)
{
    const int N = in_sizes[0];
    const int E = in_sizes[1];
    const int* gate = (const int*)d_in[0];
    const int* src = (const int*)d_in[1];
    const int* dst = (const int*)d_in[2];
    const float* sidx = (const float*)d_in[3];
    const float* didx = (const float*)d_in[4];
    const float* rev = (const float*)d_in[5];
    const float* emb = (const float*)d_in[6];
    const float* w1[5] = {(const float*)d_in[7], (const float*)d_in[10], (const float*)d_in[13],
                          (const float*)d_in[16], (const float*)d_in[19]};
    const float* w2[5] = {(const float*)d_in[8], (const float*)d_in[11], (const float*)d_in[14],
                          (const float*)d_in[17], (const float*)d_in[20]};
    const float* b2[5] = {(const float*)d_in[9], (const float*)d_in[12], (const float*)d_in[15],
                          (const float*)d_in[18], (const float*)d_in[21]};

    char* ws = (char*)d_ws;
    size_t off = 0;
    auto alloc = [&](size_t bytes) {
        void* p = ws + off;
        off = (off + bytes + 255) & ~(size_t)255;
        return p;
    };
    u16* hb0 = (u16*)alloc((size_t)N * 128 * 2);
    u16* hb1 = (u16*)alloc((size_t)N * 128 * 2);
    u16* hN = (u16*)alloc((size_t)N * 128 * 2);
    u16* g = (u16*)alloc((size_t)N * 128 * 2);        // fp16
    int* cnt = (int*)alloc((size_t)N * 4);
    int* row_off = (int*)alloc((size_t)(N + 1) * 4);
    int* cursor = (int*)alloc((size_t)N * 4);
    int4* payload = (int4*)alloc((size_t)E * 16);
    int* partial = (int*)alloc(512 * 4);
    float* invd = (float*)alloc((size_t)N * 4);
    float* w1e = (float*)alloc(5 * 384 * 4);
    u16* w1b[5];
    u16* w2b[5];
    const int fis[5] = {64, 128, 128, 128, 128};
    for (int i = 0; i < 5; i++) w1b[i] = (u16*)alloc((size_t)128 * fis[i] * 2);
    for (int i = 0; i < 5; i++) {
        int fo = (i == 4) ? 64 : 128;
        w2b[i] = (u16*)alloc((size_t)fo * (fis[i] + 128) * 2);
    }

    // weight conversions (one launch)
    WDesc wd;
    for (int i = 0; i < 5; i++) {
        wd.src[i] = w1[i]; wd.dst[i] = w1b[i];
        wd.scols[i] = fis[i] + 3; wd.dcols[i] = fis[i]; wd.n[i] = 128 * fis[i];
        int fo = (i == 4) ? 64 : 128;
        wd.src[5 + i] = w2[i]; wd.dst[5 + i] = w2b[i];
        wd.scols[5 + i] = fis[i] + 128; wd.dcols[5 + i] = fis[i] + 128;
        wd.n[5 + i] = fo * (fis[i] + 128);
    }
    k_wconv<<<dim3(128, 10), dim3(256), 0, stream>>>(wd);

    EDesc ed;
    for (int i = 0; i < 5; i++) {
        ed.src[i] = w1[i];
        ed.dst[i] = w1e + i * 384;
        ed.ldw[i] = fis[i] + 3;
        ed.fi[i] = fis[i];
    }
    k_wedge<<<dim3(5), dim3(384), 0, stream>>>(ed);

    hipMemsetAsync(cnt, 0, (size_t)N * 4, stream);
    k_count<<<dim3((E + 255) / 256), dim3(256), 0, stream>>>(dst, cnt, E);
    const int nb = (N + 255) / 256;
    k_scan1<<<dim3(nb), dim3(256), 0, stream>>>(cnt, partial, N);
    k_scan2<<<dim3(1), dim3(512), 0, stream>>>(partial, nb);
    k_scan3<<<dim3(nb), dim3(256), 0, stream>>>(cnt, partial, row_off, cursor, invd, N, E);
    k_scatter<<<dim3((E + 255) / 256), dim3(256), 0, stream>>>(dst, src, sidx, didx, rev, cursor, payload, E);
    k_emb<<<dim3((N * 64 + 255) / 256), dim3(256), 0, stream>>>(gate, emb, hb0, N);

    u16* hcur = hb0;
    u16* hnxt = hb1;
    const int gg = (N + 127) / 128;
    const int eg = (N + 3) / 4;   // 4 waves/block, 1 node/wave

    // ---- layer 1 (fi=64) ----
    k_mfma<64, 128, 64, 0, 0, 2><<<dim3(gg), dim3(256), 0, stream>>>(
        N, hcur, 64, (const u16*)nullptr, 0, w1b[0], (const float*)nullptr, g, 128);
    k_edge<<<dim3(eg), dim3(256), 0, stream>>>(N, row_off, payload, g, w1e + 0 * 384, invd, hN);
    k_mfma<192, 128, 64, 1, 1, 1><<<dim3(gg), dim3(256), 0, stream>>>(
        N, hcur, 64, hN, 128, w2b[0], b2[0], hnxt, 128);
    hcur = hb1; hnxt = hb0;

    // ---- layers 2..4 (fi=128) ----
    for (int l = 1; l < 4; ++l) {
        k_mfma<128, 128, 128, 0, 0, 2><<<dim3(gg), dim3(256), 0, stream>>>(
            N, hcur, 128, (const u16*)nullptr, 0, w1b[l], (const float*)nullptr, g, 128);
        k_edge<<<dim3(eg), dim3(256), 0, stream>>>(N, row_off, payload, g, w1e + l * 384, invd, hN);
        k_mfma<256, 128, 128, 1, 1, 1><<<dim3(gg), dim3(256), 0, stream>>>(
            N, hcur, 128, hN, 128, w2b[l], b2[l], hnxt, 128);
        u16* tmp = hcur; hcur = hnxt; hnxt = tmp;
    }

    // ---- layer 5 (fi=128, out 64 fp32, no relu) ----
    k_mfma<128, 128, 128, 0, 0, 2><<<dim3(gg), dim3(256), 0, stream>>>(
        N, hcur, 128, (const u16*)nullptr, 0, w1b[4], (const float*)nullptr, g, 128);
    k_edge<<<dim3(eg), dim3(256), 0, stream>>>(N, row_off, payload, g, w1e + 4 * 384, invd, hN);
    k_mfma<256, 64, 128, 1, 0, 0><<<dim3(gg), dim3(256), 0, stream>>>(
        N, hcur, 128, hN, 128, w2b[4], b2[4], (float*)d_out, 64);
}

// Round 8
// 454.777 us; speedup vs baseline: 3.6926x; 1.0842x over previous
//
#include <hip/hip_runtime.h>
#include <hip/hip_fp16.h>

typedef __attribute__((ext_vector_type(8))) short short8;
typedef __attribute__((ext_vector_type(4))) float f32x4;
typedef unsigned short u16;

__device__ __forceinline__ u16 f2bf(float f) {
    unsigned u = __float_as_uint(f);
    unsigned r = ((u >> 16) & 1) + 0x7FFFu;
    return (u16)((u + r) >> 16);
}

__device__ __forceinline__ void gload_lds16(const void* g, void* l) {
    __builtin_amdgcn_global_load_lds((const __attribute__((address_space(1))) unsigned int*)g,
                                     (__attribute__((address_space(3))) unsigned int*)l,
                                     16, 0, 0);
}

// packed fp16 ops (VOP3P)
__device__ __forceinline__ unsigned pk_fma(unsigned a, unsigned b, unsigned c) {
    unsigned d;
    asm("v_pk_fma_f16 %0, %1, %2, %3" : "=v"(d) : "v"(a), "v"(b), "v"(c));
    return d;
}
__device__ __forceinline__ unsigned pk_mul(unsigned a, unsigned b) {
    unsigned d;
    asm("v_pk_mul_f16 %0, %1, %2" : "=v"(d) : "v"(a), "v"(b));
    return d;
}
__device__ __forceinline__ unsigned pk_max(unsigned a, unsigned b) {
    unsigned d;
    asm("v_pk_max_f16 %0, %1, %2" : "=v"(d) : "v"(a), "v"(b));
    return d;
}

// ---------------- CSR build kernels ----------------

__global__ void k_count(const int* __restrict__ dst, int* __restrict__ cnt, int E) {
    int i = blockIdx.x * 256 + threadIdx.x;
    if (i < E) atomicAdd(&cnt[dst[i]], 1);
}

__global__ void k_scan1(const int* __restrict__ cnt, int* __restrict__ partial, int N) {
    __shared__ int sm[256];
    int idx = blockIdx.x * 256 + threadIdx.x;
    sm[threadIdx.x] = (idx < N) ? cnt[idx] : 0;
    __syncthreads();
    for (int s = 128; s > 0; s >>= 1) {
        if (threadIdx.x < s) sm[threadIdx.x] += sm[threadIdx.x + s];
        __syncthreads();
    }
    if (threadIdx.x == 0) partial[blockIdx.x] = sm[0];
}

__global__ void k_scan2(int* __restrict__ partial, int nb) {
    __shared__ int sm[512];
    int t = threadIdx.x;
    sm[t] = (t < nb) ? partial[t] : 0;
    __syncthreads();
    for (int off = 1; off < 512; off <<= 1) {
        int v = (t >= off) ? sm[t - off] : 0;
        __syncthreads();
        sm[t] += v;
        __syncthreads();
    }
    if (t < nb) partial[t] = (t == 0) ? 0 : sm[t - 1];  // exclusive
}

__global__ void k_scan3(const int* __restrict__ cnt, const int* __restrict__ partial,
                        int* __restrict__ row_off, int* __restrict__ cursor,
                        float* __restrict__ invdeg, int N, int E) {
    __shared__ int sm[256];
    int idx = blockIdx.x * 256 + threadIdx.x;
    int v = (idx < N) ? cnt[idx] : 0;
    sm[threadIdx.x] = v;
    __syncthreads();
    for (int off = 1; off < 256; off <<= 1) {
        int u = (threadIdx.x >= off) ? sm[threadIdx.x - off] : 0;
        __syncthreads();
        sm[threadIdx.x] += u;
        __syncthreads();
    }
    if (idx < N) {
        int excl = partial[blockIdx.x] + sm[threadIdx.x] - v;
        row_off[idx] = excl;
        cursor[idx] = excl;
        invdeg[idx] = 1.0f / (float)((v > 1) ? v : 1);
    }
    if (idx == 0) row_off[N] = E;
}

// scatter edge payload into CSR slots: {src, si_h2, di_h2, rv_h2} (broadcast half2)
__global__ void k_scatter(const int* __restrict__ dst, const int* __restrict__ src,
                          const float* __restrict__ sidx, const float* __restrict__ didx,
                          const float* __restrict__ rev,
                          int* __restrict__ cursor, int4* __restrict__ payload, int E) {
    int i = blockIdx.x * 256 + threadIdx.x;
    if (i < E) {
        int p = atomicAdd(&cursor[dst[i]], 1);
        unsigned hs = (unsigned)__half_as_ushort(__float2half_rn(sidx[i]));
        unsigned hd = (unsigned)__half_as_ushort(__float2half_rn(didx[i]));
        unsigned hr = (unsigned)__half_as_ushort(__float2half_rn(rev[i]));
        int4 v;
        v.x = src[i];
        v.y = (int)(hs * 0x10001u);
        v.z = (int)(hd * 0x10001u);
        v.w = (int)(hr * 0x10001u);
        payload[p] = v;
    }
}

// ---------------- embedding gather (bf16 out) ----------------

__global__ void k_emb(const int* __restrict__ gt, const float* __restrict__ emb,
                      u16* __restrict__ h0, int N) {
    int i = blockIdx.x * 256 + threadIdx.x;
    if (i < N * 64) {
        int n = i >> 6, f = i & 63;
        h0[i] = f2bf(emb[(gt[n] << 6) | f]);
    }
}

// ---------------- weight fp32 -> bf16 dense conversion ----------------

struct WDesc {
    const float* src[10];
    u16* dst[10];
    int scols[10];
    int dcols[10];
    int n[10];
};

__global__ void k_wconv(WDesc d) {
    int seg = blockIdx.y;
    int idx = blockIdx.x * 256 + threadIdx.x;
    if (idx < d.n[seg]) {
        int dc = d.dcols[seg];
        int r = idx / dc, c = idx % dc;
        d.dst[seg][idx] = f2bf(d.src[seg][r * d.scols[seg] + c]);
    }
}

// edge-weight cols of W1 as half2 pairs: W1h[c][j] = half2(W1[2j][fi+c], W1[2j+1][fi+c])
struct EDesc {
    const float* src[5];
    unsigned* dst[5];
    int ldw[5];
    int fi[5];
};

__global__ void k_wedge(EDesc d) {
    int l = blockIdx.x;
    int i = threadIdx.x;
    if (i < 192) {
        int c = i >> 6, j = i & 63;
        float a = d.src[l][(size_t)(2 * j) * d.ldw[l] + d.fi[l] + c];
        float b = d.src[l][(size_t)(2 * j + 1) * d.ldw[l] + d.fi[l] + c];
        unsigned lo = (unsigned)__half_as_ushort(__float2half_rn(a));
        unsigned hi = (unsigned)__half_as_ushort(__float2half_rn(b));
        d.dst[l][(c << 6) + j] = lo | (hi << 16);
    }
}

// ---------------- edge aggregation: grid-stride chunked waves, packed fp16 MLP ----------------
// wave handles consecutive node chunk; within wave: 4 edge-groups x 16 lanes, 8 feats/lane.
// v = g + W1e.w_edge in packed fp16; leaky = pk_max(v, 0.01*v); accumulate fp32.

__global__ __launch_bounds__(256)
void k_edge(int N,
            const int* __restrict__ row_off, const int4* __restrict__ payload,
            const u16* __restrict__ g,        // [N,128] fp16
            const unsigned* __restrict__ W1h, // [3][64] half2 pairs
            const float* __restrict__ invdeg,
            u16* __restrict__ hN)             // [N,128] bf16
{
    const int t = threadIdx.x;
    const int lane = t & 63;
    const int fl = lane & 15;
    const int eg = lane >> 4;
    const int wid = blockIdx.x * (blockDim.x >> 6) + (t >> 6);
    const int nwtot = gridDim.x * (blockDim.x >> 6);
    const int per = (N + nwtot - 1) / nwtot;
    const int n0 = wid * per;
    if (n0 >= N) return;
    const int n1 = (n0 + per < N) ? (n0 + per) : N;

    // hoisted weights: pairs 4fl..4fl+3 of each edge column
    const uint4 wa = *(const uint4*)&W1h[(fl << 2)];
    const uint4 wb = *(const uint4*)&W1h[64 + (fl << 2)];
    const uint4 wc = *(const uint4*)&W1h[128 + (fl << 2)];
    const unsigned c001 = ((unsigned)__half_as_ushort(__float2half_rn(0.01f))) * 0x10001u;

    int beg = row_off[n0];
    for (int n = n0; n < n1; ++n) {
        const int end = row_off[n + 1];
        float acc[8] = {0.f, 0.f, 0.f, 0.f, 0.f, 0.f, 0.f, 0.f};

        int p = beg + eg;
        int4 pl;
        if (p < end) pl = payload[p];
        while (p < end) {
            const int pn = p + 4;
            int4 plN = pl;
            if (pn < end) plN = payload[pn];
            const uint4 gv = *(const uint4*)(g + ((size_t)pl.x << 7) + (fl << 3));
            const unsigned si = (unsigned)pl.y;
            const unsigned di = (unsigned)pl.z;
            const unsigned rv = (unsigned)pl.w;
            unsigned v0 = pk_fma(wa.x, si, gv.x);
            unsigned v1 = pk_fma(wa.y, si, gv.y);
            unsigned v2 = pk_fma(wa.z, si, gv.z);
            unsigned v3 = pk_fma(wa.w, si, gv.w);
            v0 = pk_fma(wb.x, di, v0);
            v1 = pk_fma(wb.y, di, v1);
            v2 = pk_fma(wb.z, di, v2);
            v3 = pk_fma(wb.w, di, v3);
            v0 = pk_fma(wc.x, rv, v0);
            v1 = pk_fma(wc.y, rv, v1);
            v2 = pk_fma(wc.z, rv, v2);
            v3 = pk_fma(wc.w, rv, v3);
            v0 = pk_max(v0, pk_mul(v0, c001));
            v1 = pk_max(v1, pk_mul(v1, c001));
            v2 = pk_max(v2, pk_mul(v2, c001));
            v3 = pk_max(v3, pk_mul(v3, c001));
            const float2 f0 = __half22float2(*(const __half2*)&v0);
            const float2 f1 = __half22float2(*(const __half2*)&v1);
            const float2 f2 = __half22float2(*(const __half2*)&v2);
            const float2 f3 = __half22float2(*(const __half2*)&v3);
            acc[0] += f0.x; acc[1] += f0.y;
            acc[2] += f1.x; acc[3] += f1.y;
            acc[4] += f2.x; acc[5] += f2.y;
            acc[6] += f3.x; acc[7] += f3.y;
            p = pn;
            pl = plN;
        }

        // combine the 4 edge groups
#pragma unroll
        for (int r = 0; r < 8; r++) {
            acc[r] += __shfl_xor(acc[r], 16, 64);
            acc[r] += __shfl_xor(acc[r], 32, 64);
        }

        if (eg == 0) {
            const float inv = invdeg[n];
            unsigned q0 = (unsigned)f2bf(acc[0] * inv) | ((unsigned)f2bf(acc[1] * inv) << 16);
            unsigned q1 = (unsigned)f2bf(acc[2] * inv) | ((unsigned)f2bf(acc[3] * inv) << 16);
            unsigned q2 = (unsigned)f2bf(acc[4] * inv) | ((unsigned)f2bf(acc[5] * inv) << 16);
            unsigned q3 = (unsigned)f2bf(acc[6] * inv) | ((unsigned)f2bf(acc[7] * inv) << 16);
            uint4 out = make_uint4(q0, q1, q2, q3);
            *(uint4*)(hN + ((size_t)n << 7) + (fl << 3)) = out;
        }
        beg = end;
    }
}

// ---------------- bf16 MFMA GEMM ----------------
// C[M,O] = A[M,K] @ W[O,K]^T (+bias, act).  A virtual concat at SPLIT (A1/A2 bf16).
// Block: 128 rows x O cols, 256 threads = 4 waves (2x2).
// OUTDT: 0 = fp32, 1 = bf16, 2 = fp16.

template<int K, int O, int SPLIT, int BIAS, int RELU, int OUTDT>
__global__ __launch_bounds__(256)
void k_mfma(int M,
            const u16* __restrict__ A1, int lda1,
            const u16* __restrict__ A2, int lda2,
            const u16* __restrict__ Wb,     // [O][K] dense bf16
            const float* __restrict__ bias,
            void* __restrict__ Cout, int ldc)
{
    constexpr int KP = K + 8;
    constexpr int NF = O / 32;   // N-frags per wave
    constexpr int WC = O / 2;    // cols per wave
    __shared__ __align__(16) u16 Wlds[O * KP];
    __shared__ __align__(16) u16 Atile[128 * 32];

    const int t = threadIdx.x;
    const int m0 = blockIdx.x * 128;
    const int w = t >> 6, l = t & 63;
    const int wm = w & 1, wn = w >> 1;
    const int lr = l & 15, lh = l >> 4;

    // stage W (L2-resident source)
    for (int idx = t; idx < O * (K / 8); idx += 256) {
        int row = idx / (K / 8), ch = idx % (K / 8);
        uint4 v = *(const uint4*)(Wb + (size_t)row * K + ch * 8);
        *(uint4*)(&Wlds[row * KP + ch * 8]) = v;
    }

    f32x4 acc[4][NF];
#pragma unroll
    for (int mi = 0; mi < 4; mi++)
#pragma unroll
        for (int ni = 0; ni < NF; ni++) acc[mi][ni] = (f32x4){0.f, 0.f, 0.f, 0.f};

    __syncthreads();

    for (int kt = 0; kt < K / 32; ++kt) {
        const int k0 = kt * 32;
        const u16* Asrc;
        int lda, kof;
        if (k0 < SPLIT) { Asrc = A1; lda = lda1; kof = k0; }
        else            { Asrc = A2; lda = lda2; kof = k0 - SPLIT; }
#pragma unroll
        for (int q = 0; q < 2; ++q) {
            int o = q * 4096 + t * 16;        // byte offset in Atile
            int row = o >> 6, cb = o & 63;
            int m = m0 + row;
            m = (m < M) ? m : (M - 1);        // clamp tail rows (results discarded on store)
            gload_lds16(Asrc + (size_t)m * lda + kof + (cb >> 1), (void*)(Atile + (o >> 1)));
        }
        __syncthreads();   // compiler drains vmcnt before barrier

        short8 a[4], b[NF];
#pragma unroll
        for (int mi = 0; mi < 4; mi++)
            a[mi] = *(const short8*)(Atile + (wm * 64 + mi * 16 + lr) * 32 + lh * 8);
#pragma unroll
        for (int ni = 0; ni < NF; ni++)
            b[ni] = *(const short8*)(Wlds + (size_t)(wn * WC + ni * 16 + lr) * KP + k0 + lh * 8);
#pragma unroll
        for (int mi = 0; mi < 4; mi++)
#pragma unroll
            for (int ni = 0; ni < NF; ni++)
                acc[mi][ni] = __builtin_amdgcn_mfma_f32_16x16x32_bf16(a[mi], b[ni], acc[mi][ni], 0, 0, 0);
        __syncthreads();   // before next stage overwrites Atile
    }

    // epilogue: D row = (lane>>4)*4 + reg, col = lane&15
    float bv[NF];
#pragma unroll
    for (int ni = 0; ni < NF; ni++)
        bv[ni] = BIAS ? bias[wn * WC + ni * 16 + lr] : 0.f;
#pragma unroll
    for (int mi = 0; mi < 4; mi++) {
#pragma unroll
        for (int i = 0; i < 4; i++) {
            int row = m0 + wm * 64 + mi * 16 + lh * 4 + i;
            if (row < M) {
#pragma unroll
                for (int ni = 0; ni < NF; ni++) {
                    float v = acc[mi][ni][i] + bv[ni];
                    if (RELU) v = fmaxf(v, 0.f);
                    int col = wn * WC + ni * 16 + lr;
                    if (OUTDT == 1)      ((u16*)Cout)[(size_t)row * ldc + col] = f2bf(v);
                    else if (OUTDT == 2) ((__half*)Cout)[(size_t)row * ldc + col] = __float2half(v);
                    else                 ((float*)Cout)[(size_t)row * ldc + col] = v;
                }
            }
        }
    }
}

// ---------------- launcher ----------------

extern "C" void kernel_launch(void* const* d_in, const int* in_sizes, int n_in,
                              void* d_out, int out_size, void* d_ws, size_t ws_size,
                              hipStream_t stream)
{
    const int N = in_sizes[0];
    const int E = in_sizes[1];
    const int* gate = (const int*)d_in[0];
    const int* src = (const int*)d_in[1];
    const int* dst = (const int*)d_in[2];
    const float* sidx = (const float*)d_in[3];
    const float* didx = (const float*)d_in[4];
    const float* rev = (const float*)d_in[5];
    const float* emb = (const float*)d_in[6];
    const float* w1[5] = {(const float*)d_in[7], (const float*)d_in[10], (const float*)d_in[13],
                          (const float*)d_in[16], (const float*)d_in[19]};
    const float* w2[5] = {(const float*)d_in[8], (const float*)d_in[11], (const float*)d_in[14],
                          (const float*)d_in[17], (const float*)d_in[20]};
    const float* b2[5] = {(const float*)d_in[9], (const float*)d_in[12], (const float*)d_in[15],
                          (const float*)d_in[18], (const float*)d_in[21]};

    char* ws = (char*)d_ws;
    size_t off = 0;
    auto alloc = [&](size_t bytes) {
        void* p = ws + off;
        off = (off + bytes + 255) & ~(size_t)255;
        return p;
    };
    u16* hb0 = (u16*)alloc((size_t)N * 128 * 2);
    u16* hb1 = (u16*)alloc((size_t)N * 128 * 2);
    u16* hN = (u16*)alloc((size_t)N * 128 * 2);
    u16* g = (u16*)alloc((size_t)N * 128 * 2);        // fp16
    int* cnt = (int*)alloc((size_t)N * 4);
    int* row_off = (int*)alloc((size_t)(N + 1) * 4);
    int* cursor = (int*)alloc((size_t)N * 4);
    int4* payload = (int4*)alloc((size_t)E * 16);
    int* partial = (int*)alloc(512 * 4);
    float* invd = (float*)alloc((size_t)N * 4);
    unsigned* w1h = (unsigned*)alloc(5 * 192 * 4);
    u16* w1b[5];
    u16* w2b[5];
    const int fis[5] = {64, 128, 128, 128, 128};
    for (int i = 0; i < 5; i++) w1b[i] = (u16*)alloc((size_t)128 * fis[i] * 2);
    for (int i = 0; i < 5; i++) {
        int fo = (i == 4) ? 64 : 128;
        w2b[i] = (u16*)alloc((size_t)fo * (fis[i] + 128) * 2);
    }

    // weight conversions (one launch)
    WDesc wd;
    for (int i = 0; i < 5; i++) {
        wd.src[i] = w1[i]; wd.dst[i] = w1b[i];
        wd.scols[i] = fis[i] + 3; wd.dcols[i] = fis[i]; wd.n[i] = 128 * fis[i];
        int fo = (i == 4) ? 64 : 128;
        wd.src[5 + i] = w2[i]; wd.dst[5 + i] = w2b[i];
        wd.scols[5 + i] = fis[i] + 128; wd.dcols[5 + i] = fis[i] + 128;
        wd.n[5 + i] = fo * (fis[i] + 128);
    }
    k_wconv<<<dim3(128, 10), dim3(256), 0, stream>>>(wd);

    EDesc ed;
    for (int i = 0; i < 5; i++) {
        ed.src[i] = w1[i];
        ed.dst[i] = w1h + i * 192;
        ed.ldw[i] = fis[i] + 3;
        ed.fi[i] = fis[i];
    }
    k_wedge<<<dim3(5), dim3(192), 0, stream>>>(ed);

    hipMemsetAsync(cnt, 0, (size_t)N * 4, stream);
    k_count<<<dim3((E + 255) / 256), dim3(256), 0, stream>>>(dst, cnt, E);
    const int nb = (N + 255) / 256;
    k_scan1<<<dim3(nb), dim3(256), 0, stream>>>(cnt, partial, N);
    k_scan2<<<dim3(1), dim3(512), 0, stream>>>(partial, nb);
    k_scan3<<<dim3(nb), dim3(256), 0, stream>>>(cnt, partial, row_off, cursor, invd, N, E);
    k_scatter<<<dim3((E + 255) / 256), dim3(256), 0, stream>>>(dst, src, sidx, didx, rev, cursor, payload, E);
    k_emb<<<dim3((N * 64 + 255) / 256), dim3(256), 0, stream>>>(gate, emb, hb0, N);

    u16* hcur = hb0;
    u16* hnxt = hb1;
    const int gg = (N + 127) / 128;
    const int eb = 2048;   // grid-stride chunked waves (8192 waves, ~13 nodes each)

    // ---- layer 1 (fi=64) ----
    k_mfma<64, 128, 64, 0, 0, 2><<<dim3(gg), dim3(256), 0, stream>>>(
        N, hcur, 64, (const u16*)nullptr, 0, w1b[0], (const float*)nullptr, g, 128);
    k_edge<<<dim3(eb), dim3(256), 0, stream>>>(N, row_off, payload, g, w1h + 0 * 192, invd, hN);
    k_mfma<192, 128, 64, 1, 1, 1><<<dim3(gg), dim3(256), 0, stream>>>(
        N, hcur, 64, hN, 128, w2b[0], b2[0], hnxt, 128);
    hcur = hb1; hnxt = hb0;

    // ---- layers 2..4 (fi=128) ----
    for (int l = 1; l < 4; ++l) {
        k_mfma<128, 128, 128, 0, 0, 2><<<dim3(gg), dim3(256), 0, stream>>>(
            N, hcur, 128, (const u16*)nullptr, 0, w1b[l], (const float*)nullptr, g, 128);
        k_edge<<<dim3(eb), dim3(256), 0, stream>>>(N, row_off, payload, g, w1h + l * 192, invd, hN);
        k_mfma<256, 128, 128, 1, 1, 1><<<dim3(gg), dim3(256), 0, stream>>>(
            N, hcur, 128, hN, 128, w2b[l], b2[l], hnxt, 128);
        u16* tmp = hcur; hcur = hnxt; hnxt = tmp;
    }

    // ---- layer 5 (fi=128, out 64 fp32, no relu) ----
    k_mfma<128, 128, 128, 0, 0, 2><<<dim3(gg), dim3(256), 0, stream>>>(
        N, hcur, 128, (const u16*)nullptr, 0, w1b[4], (const float*)nullptr, g, 128);
    k_edge<<<dim3(eb), dim3(256), 0, stream>>>(N, row_off, payload, g, w1h + 4 * 192, invd, hN);
    k_mfma<256, 64, 128, 1, 0, 0><<<dim3(gg), dim3(256), 0, stream>>>(
        N, hcur, 128, hN, 128, w2b[4], b2[4], (float*)d_out, 64);
}

// Round 9
// 426.378 us; speedup vs baseline: 3.9385x; 1.0666x over previous
//
#include <hip/hip_runtime.h>
#include <hip/hip_fp16.h>

typedef __attribute__((ext_vector_type(8))) short short8;
typedef __attribute__((ext_vector_type(4))) float f32x4;
typedef unsigned short u16;

__device__ __forceinline__ u16 f2bf(float f) {
    unsigned u = __float_as_uint(f);
    unsigned r = ((u >> 16) & 1) + 0x7FFFu;
    return (u16)((u + r) >> 16);
}

__device__ __forceinline__ void gload_lds16(const void* g, void* l) {
    __builtin_amdgcn_global_load_lds((const __attribute__((address_space(1))) unsigned int*)g,
                                     (__attribute__((address_space(3))) unsigned int*)l,
                                     16, 0, 0);
}

// packed fp16 ops (VOP3P)
__device__ __forceinline__ unsigned pk_fma(unsigned a, unsigned b, unsigned c) {
    unsigned d;
    asm("v_pk_fma_f16 %0, %1, %2, %3" : "=v"(d) : "v"(a), "v"(b), "v"(c));
    return d;
}
__device__ __forceinline__ unsigned pk_mul(unsigned a, unsigned b) {
    unsigned d;
    asm("v_pk_mul_f16 %0, %1, %2" : "=v"(d) : "v"(a), "v"(b));
    return d;
}
__device__ __forceinline__ unsigned pk_max(unsigned a, unsigned b) {
    unsigned d;
    asm("v_pk_max_f16 %0, %1, %2" : "=v"(d) : "v"(a), "v"(b));
    return d;
}

// ---------------- CSR build kernels ----------------

__global__ void k_count(const int* __restrict__ dst, int* __restrict__ cnt, int E) {
    int i = blockIdx.x * 256 + threadIdx.x;
    if (i < E) atomicAdd(&cnt[dst[i]], 1);
}

__global__ void k_scan1(const int* __restrict__ cnt, int* __restrict__ partial, int N) {
    __shared__ int sm[256];
    int idx = blockIdx.x * 256 + threadIdx.x;
    sm[threadIdx.x] = (idx < N) ? cnt[idx] : 0;
    __syncthreads();
    for (int s = 128; s > 0; s >>= 1) {
        if (threadIdx.x < s) sm[threadIdx.x] += sm[threadIdx.x + s];
        __syncthreads();
    }
    if (threadIdx.x == 0) partial[blockIdx.x] = sm[0];
}

__global__ void k_scan2(int* __restrict__ partial, int nb) {
    __shared__ int sm[512];
    int t = threadIdx.x;
    sm[t] = (t < nb) ? partial[t] : 0;
    __syncthreads();
    for (int off = 1; off < 512; off <<= 1) {
        int v = (t >= off) ? sm[t - off] : 0;
        __syncthreads();
        sm[t] += v;
        __syncthreads();
    }
    if (t < nb) partial[t] = (t == 0) ? 0 : sm[t - 1];  // exclusive
}

__global__ void k_scan3(const int* __restrict__ cnt, const int* __restrict__ partial,
                        int* __restrict__ row_off, int* __restrict__ cursor,
                        float* __restrict__ invdeg, int N, int E) {
    __shared__ int sm[256];
    int idx = blockIdx.x * 256 + threadIdx.x;
    int v = (idx < N) ? cnt[idx] : 0;
    sm[threadIdx.x] = v;
    __syncthreads();
    for (int off = 1; off < 256; off <<= 1) {
        int u = (threadIdx.x >= off) ? sm[threadIdx.x - off] : 0;
        __syncthreads();
        sm[threadIdx.x] += u;
        __syncthreads();
    }
    if (idx < N) {
        int excl = partial[blockIdx.x] + sm[threadIdx.x] - v;
        row_off[idx] = excl;
        cursor[idx] = excl;
        invdeg[idx] = 1.0f / (float)((v > 1) ? v : 1);
    }
    if (idx == 0) row_off[N] = E;
}

// scatter edge payload into CSR slots: {src, si_h2, di_h2, rv_h2} (broadcast half2)
__global__ void k_scatter(const int* __restrict__ dst, const int* __restrict__ src,
                          const float* __restrict__ sidx, const float* __restrict__ didx,
                          const float* __restrict__ rev,
                          int* __restrict__ cursor, int4* __restrict__ payload, int E) {
    int i = blockIdx.x * 256 + threadIdx.x;
    if (i < E) {
        int p = atomicAdd(&cursor[dst[i]], 1);
        unsigned hs = (unsigned)__half_as_ushort(__float2half_rn(sidx[i]));
        unsigned hd = (unsigned)__half_as_ushort(__float2half_rn(didx[i]));
        unsigned hr = (unsigned)__half_as_ushort(__float2half_rn(rev[i]));
        int4 v;
        v.x = src[i];
        v.y = (int)(hs * 0x10001u);
        v.z = (int)(hd * 0x10001u);
        v.w = (int)(hr * 0x10001u);
        payload[p] = v;
    }
}

// ---------------- embedding gather (bf16 out) ----------------

__global__ void k_emb(const int* __restrict__ gt, const float* __restrict__ emb,
                      u16* __restrict__ h0, int N) {
    int i = blockIdx.x * 256 + threadIdx.x;
    if (i < N * 64) {
        int n = i >> 6, f = i & 63;
        h0[i] = f2bf(emb[(gt[n] << 6) | f]);
    }
}

// ---------------- weight fp32 -> bf16 dense conversion ----------------

struct WDesc {
    const float* src[10];
    u16* dst[10];
    int scols[10];
    int dcols[10];
    int n[10];
};

__global__ void k_wconv(WDesc d) {
    int seg = blockIdx.y;
    int idx = blockIdx.x * 256 + threadIdx.x;
    if (idx < d.n[seg]) {
        int dc = d.dcols[seg];
        int r = idx / dc, c = idx % dc;
        d.dst[seg][idx] = f2bf(d.src[seg][r * d.scols[seg] + c]);
    }
}

// edge-weight cols of W1 as half2 pairs: W1h[c][j] = half2(W1[2j][fi+c], W1[2j+1][fi+c])
struct EDesc {
    const float* src[5];
    unsigned* dst[5];
    int ldw[5];
    int fi[5];
};

__global__ void k_wedge(EDesc d) {
    int l = blockIdx.x;
    int i = threadIdx.x;
    if (i < 192) {
        int c = i >> 6, j = i & 63;
        float a = d.src[l][(size_t)(2 * j) * d.ldw[l] + d.fi[l] + c];
        float b = d.src[l][(size_t)(2 * j + 1) * d.ldw[l] + d.fi[l] + c];
        unsigned lo = (unsigned)__half_as_ushort(__float2half_rn(a));
        unsigned hi = (unsigned)__half_as_ushort(__float2half_rn(b));
        d.dst[l][(c << 6) + j] = lo | (hi << 16);
    }
}

// ---------------- edge aggregation: grid-stride chunked waves, packed fp16 MLP ----------------

__global__ __launch_bounds__(256)
void k_edge(int N,
            const int* __restrict__ row_off, const int4* __restrict__ payload,
            const u16* __restrict__ g,        // [N,128] fp16
            const unsigned* __restrict__ W1h, // [3][64] half2 pairs
            const float* __restrict__ invdeg,
            u16* __restrict__ hN)             // [N,128] bf16
{
    const int t = threadIdx.x;
    const int lane = t & 63;
    const int fl = lane & 15;
    const int eg = lane >> 4;
    const int wid = blockIdx.x * (blockDim.x >> 6) + (t >> 6);
    const int nwtot = gridDim.x * (blockDim.x >> 6);
    const int per = (N + nwtot - 1) / nwtot;
    const int n0 = wid * per;
    if (n0 >= N) return;
    const int n1 = (n0 + per < N) ? (n0 + per) : N;

    const uint4 wa = *(const uint4*)&W1h[(fl << 2)];
    const uint4 wb = *(const uint4*)&W1h[64 + (fl << 2)];
    const uint4 wc = *(const uint4*)&W1h[128 + (fl << 2)];
    const unsigned c001 = ((unsigned)__half_as_ushort(__float2half_rn(0.01f))) * 0x10001u;

    int beg = row_off[n0];
    for (int n = n0; n < n1; ++n) {
        const int end = row_off[n + 1];
        float acc[8] = {0.f, 0.f, 0.f, 0.f, 0.f, 0.f, 0.f, 0.f};

        int p = beg + eg;
        int4 pl;
        if (p < end) pl = payload[p];
        while (p < end) {
            const int pn = p + 4;
            int4 plN = pl;
            if (pn < end) plN = payload[pn];
            const uint4 gv = *(const uint4*)(g + ((size_t)pl.x << 7) + (fl << 3));
            const unsigned si = (unsigned)pl.y;
            const unsigned di = (unsigned)pl.z;
            const unsigned rv = (unsigned)pl.w;
            unsigned v0 = pk_fma(wa.x, si, gv.x);
            unsigned v1 = pk_fma(wa.y, si, gv.y);
            unsigned v2 = pk_fma(wa.z, si, gv.z);
            unsigned v3 = pk_fma(wa.w, si, gv.w);
            v0 = pk_fma(wb.x, di, v0);
            v1 = pk_fma(wb.y, di, v1);
            v2 = pk_fma(wb.z, di, v2);
            v3 = pk_fma(wb.w, di, v3);
            v0 = pk_fma(wc.x, rv, v0);
            v1 = pk_fma(wc.y, rv, v1);
            v2 = pk_fma(wc.z, rv, v2);
            v3 = pk_fma(wc.w, rv, v3);
            v0 = pk_max(v0, pk_mul(v0, c001));
            v1 = pk_max(v1, pk_mul(v1, c001));
            v2 = pk_max(v2, pk_mul(v2, c001));
            v3 = pk_max(v3, pk_mul(v3, c001));
            const float2 f0 = __half22float2(*(const __half2*)&v0);
            const float2 f1 = __half22float2(*(const __half2*)&v1);
            const float2 f2 = __half22float2(*(const __half2*)&v2);
            const float2 f3 = __half22float2(*(const __half2*)&v3);
            acc[0] += f0.x; acc[1] += f0.y;
            acc[2] += f1.x; acc[3] += f1.y;
            acc[4] += f2.x; acc[5] += f2.y;
            acc[6] += f3.x; acc[7] += f3.y;
            p = pn;
            pl = plN;
        }

#pragma unroll
        for (int r = 0; r < 8; r++) {
            acc[r] += __shfl_xor(acc[r], 16, 64);
            acc[r] += __shfl_xor(acc[r], 32, 64);
        }

        if (eg == 0) {
            const float inv = invdeg[n];
            unsigned q0 = (unsigned)f2bf(acc[0] * inv) | ((unsigned)f2bf(acc[1] * inv) << 16);
            unsigned q1 = (unsigned)f2bf(acc[2] * inv) | ((unsigned)f2bf(acc[3] * inv) << 16);
            unsigned q2 = (unsigned)f2bf(acc[4] * inv) | ((unsigned)f2bf(acc[5] * inv) << 16);
            unsigned q3 = (unsigned)f2bf(acc[6] * inv) | ((unsigned)f2bf(acc[7] * inv) << 16);
            uint4 out = make_uint4(q0, q1, q2, q3);
            *(uint4*)(hN + ((size_t)n << 7) + (fl << 3)) = out;
        }
        beg = end;
    }
}

// ---------------- bf16 MFMA GEMM (standalone) ----------------
// C[M,O] = A[M,K] @ W[O,K]^T (+bias, act).  OUTDT: 0 = fp32, 1 = bf16, 2 = fp16.

template<int K, int O, int SPLIT, int BIAS, int RELU, int OUTDT>
__global__ __launch_bounds__(256)
void k_mfma(int M,
            const u16* __restrict__ A1, int lda1,
            const u16* __restrict__ A2, int lda2,
            const u16* __restrict__ Wb,     // [O][K] dense bf16
            const float* __restrict__ bias,
            void* __restrict__ Cout, int ldc)
{
    constexpr int KP = K + 8;
    constexpr int NF = O / 32;
    constexpr int WC = O / 2;
    __shared__ __align__(16) u16 Wlds[O * KP];
    __shared__ __align__(16) u16 Atile[128 * 32];

    const int t = threadIdx.x;
    const int m0 = blockIdx.x * 128;
    const int w = t >> 6, l = t & 63;
    const int wm = w & 1, wn = w >> 1;
    const int lr = l & 15, lh = l >> 4;

    for (int idx = t; idx < O * (K / 8); idx += 256) {
        int row = idx / (K / 8), ch = idx % (K / 8);
        uint4 v = *(const uint4*)(Wb + (size_t)row * K + ch * 8);
        *(uint4*)(&Wlds[row * KP + ch * 8]) = v;
    }

    f32x4 acc[4][NF];
#pragma unroll
    for (int mi = 0; mi < 4; mi++)
#pragma unroll
        for (int ni = 0; ni < NF; ni++) acc[mi][ni] = (f32x4){0.f, 0.f, 0.f, 0.f};

    __syncthreads();

    for (int kt = 0; kt < K / 32; ++kt) {
        const int k0 = kt * 32;
        const u16* Asrc;
        int lda, kof;
        if (k0 < SPLIT) { Asrc = A1; lda = lda1; kof = k0; }
        else            { Asrc = A2; lda = lda2; kof = k0 - SPLIT; }
#pragma unroll
        for (int q = 0; q < 2; ++q) {
            int o = q * 4096 + t * 16;
            int row = o >> 6, cb = o & 63;
            int m = m0 + row;
            m = (m < M) ? m : (M - 1);
            gload_lds16(Asrc + (size_t)m * lda + kof + (cb >> 1), (void*)(Atile + (o >> 1)));
        }
        __syncthreads();

        short8 a[4], b[NF];
#pragma unroll
        for (int mi = 0; mi < 4; mi++)
            a[mi] = *(const short8*)(Atile + (wm * 64 + mi * 16 + lr) * 32 + lh * 8);
#pragma unroll
        for (int ni = 0; ni < NF; ni++)
            b[ni] = *(const short8*)(Wlds + (size_t)(wn * WC + ni * 16 + lr) * KP + k0 + lh * 8);
#pragma unroll
        for (int mi = 0; mi < 4; mi++)
#pragma unroll
            for (int ni = 0; ni < NF; ni++)
                acc[mi][ni] = __builtin_amdgcn_mfma_f32_16x16x32_bf16(a[mi], b[ni], acc[mi][ni], 0, 0, 0);
        __syncthreads();
    }

    float bv[NF];
#pragma unroll
    for (int ni = 0; ni < NF; ni++)
        bv[ni] = BIAS ? bias[wn * WC + ni * 16 + lr] : 0.f;
#pragma unroll
    for (int mi = 0; mi < 4; mi++) {
#pragma unroll
        for (int i = 0; i < 4; i++) {
            int row = m0 + wm * 64 + mi * 16 + lh * 4 + i;
            if (row < M) {
#pragma unroll
                for (int ni = 0; ni < NF; ni++) {
                    float v = acc[mi][ni][i] + bv[ni];
                    if (RELU) v = fmaxf(v, 0.f);
                    int col = wn * WC + ni * 16 + lr;
                    if (OUTDT == 1)      ((u16*)Cout)[(size_t)row * ldc + col] = f2bf(v);
                    else if (OUTDT == 2) ((__half*)Cout)[(size_t)row * ldc + col] = __float2half(v);
                    else                 ((float*)Cout)[(size_t)row * ldc + col] = v;
                }
            }
        }
    }
}

// ---------------- fused W2-GEMM + next-layer g-GEMM ----------------
// Phase 1: h' = relu([A1,A2] @ W2^T + b2)  (128x128 tile, bf16 out to global + LDS Htile)
// Phase 2: g  = h' @ W1a_next^T            (K2=128, fp16 out)
// LDS: union { phase1 Wlds[128][K+8] | phase2 Htile[128][136] + Wg[128][136] } + Atile.

template<int K, int SPLIT>
__global__ __launch_bounds__(256)
void k_mfma_fused(int M,
                  const u16* __restrict__ A1, int lda1,
                  const u16* __restrict__ A2, int lda2,
                  const u16* __restrict__ Wb,   // W2 [128][K] bf16
                  const float* __restrict__ bias,
                  u16* __restrict__ Hout,       // h' bf16 [M][128]
                  const u16* __restrict__ Wg,   // W1a next [128][128] bf16
                  u16* __restrict__ Gout)       // g fp16 [M][128]
{
    constexpr int KP = K + 8;
    constexpr int HP = 136;      // Htile/Wg row stride (u16), 272B = 17*16B
    __shared__ __align__(16) char U[(128 * HP * 2) * 2 + 128 * 32 * 2];  // 69632 + 8192
    u16* Wlds  = (u16*)U;                         // phase 1 (<= 67584 B)
    u16* Htile = (u16*)U;                         // phase 2 [128][136]
    u16* Wglds = (u16*)(U + 128 * HP * 2);        // phase 2 [128][136]
    u16* Atile = (u16*)(U + 2 * 128 * HP * 2);    // phase 1 staging

    const int t = threadIdx.x;
    const int m0 = blockIdx.x * 128;
    const int w = t >> 6, l = t & 63;
    const int wm = w & 1, wn = w >> 1;
    const int lr = l & 15, lh = l >> 4;

    for (int idx = t; idx < 128 * (K / 8); idx += 256) {
        int row = idx / (K / 8), ch = idx % (K / 8);
        uint4 v = *(const uint4*)(Wb + (size_t)row * K + ch * 8);
        *(uint4*)(&Wlds[row * KP + ch * 8]) = v;
    }

    f32x4 acc[4][4];
#pragma unroll
    for (int mi = 0; mi < 4; mi++)
#pragma unroll
        for (int ni = 0; ni < 4; ni++) acc[mi][ni] = (f32x4){0.f, 0.f, 0.f, 0.f};

    __syncthreads();

    for (int kt = 0; kt < K / 32; ++kt) {
        const int k0 = kt * 32;
        const u16* Asrc;
        int lda, kof;
        if (k0 < SPLIT) { Asrc = A1; lda = lda1; kof = k0; }
        else            { Asrc = A2; lda = lda2; kof = k0 - SPLIT; }
#pragma unroll
        for (int q = 0; q < 2; ++q) {
            int o = q * 4096 + t * 16;
            int row = o >> 6, cb = o & 63;
            int m = m0 + row;
            m = (m < M) ? m : (M - 1);
            gload_lds16(Asrc + (size_t)m * lda + kof + (cb >> 1), (void*)(Atile + (o >> 1)));
        }
        __syncthreads();

        short8 a[4], b[4];
#pragma unroll
        for (int mi = 0; mi < 4; mi++)
            a[mi] = *(const short8*)(Atile + (wm * 64 + mi * 16 + lr) * 32 + lh * 8);
#pragma unroll
        for (int ni = 0; ni < 4; ni++)
            b[ni] = *(const short8*)(Wlds + (size_t)(wn * 64 + ni * 16 + lr) * KP + k0 + lh * 8);
#pragma unroll
        for (int mi = 0; mi < 4; mi++)
#pragma unroll
            for (int ni = 0; ni < 4; ni++)
                acc[mi][ni] = __builtin_amdgcn_mfma_f32_16x16x32_bf16(a[mi], b[ni], acc[mi][ni], 0, 0, 0);
        __syncthreads();   // all waves past last Wlds read -> safe to overlay
    }

    // stage Wg for phase 2 (issue early; overlaps epilogue VALU)
    for (int idx = t; idx < 128 * 16; idx += 256) {
        int row = idx >> 4, ch = idx & 15;
        uint4 v = *(const uint4*)(Wg + (size_t)row * 128 + ch * 8);
        *(uint4*)(&Wglds[row * HP + ch * 8]) = v;
    }

    // phase-1 epilogue: bias+relu, write global h' AND LDS Htile (bf16)
    float bv[4];
#pragma unroll
    for (int ni = 0; ni < 4; ni++) bv[ni] = bias[wn * 64 + ni * 16 + lr];
#pragma unroll
    for (int mi = 0; mi < 4; mi++) {
#pragma unroll
        for (int i = 0; i < 4; i++) {
            int rloc = wm * 64 + mi * 16 + lh * 4 + i;
            int row = m0 + rloc;
#pragma unroll
            for (int ni = 0; ni < 4; ni++) {
                float v = fmaxf(acc[mi][ni][i] + bv[ni], 0.f);
                u16 hv = f2bf(v);
                int col = wn * 64 + ni * 16 + lr;
                Htile[rloc * HP + col] = hv;
                if (row < M) Hout[(size_t)row * 128 + col] = hv;
            }
        }
    }
    __syncthreads();

    // phase 2: g = Htile @ Wg^T (K2 = 128)
    f32x4 acc2[4][4];
#pragma unroll
    for (int mi = 0; mi < 4; mi++)
#pragma unroll
        for (int ni = 0; ni < 4; ni++) acc2[mi][ni] = (f32x4){0.f, 0.f, 0.f, 0.f};

#pragma unroll
    for (int kt = 0; kt < 4; ++kt) {
        const int k0 = kt * 32;
        short8 a[4], b[4];
#pragma unroll
        for (int mi = 0; mi < 4; mi++)
            a[mi] = *(const short8*)(Htile + (wm * 64 + mi * 16 + lr) * HP + k0 + lh * 8);
#pragma unroll
        for (int ni = 0; ni < 4; ni++)
            b[ni] = *(const short8*)(Wglds + (wn * 64 + ni * 16 + lr) * HP + k0 + lh * 8);
#pragma unroll
        for (int mi = 0; mi < 4; mi++)
#pragma unroll
            for (int ni = 0; ni < 4; ni++)
                acc2[mi][ni] = __builtin_amdgcn_mfma_f32_16x16x32_bf16(a[mi], b[ni], acc2[mi][ni], 0, 0, 0);
    }

#pragma unroll
    for (int mi = 0; mi < 4; mi++) {
#pragma unroll
        for (int i = 0; i < 4; i++) {
            int row = m0 + wm * 64 + mi * 16 + lh * 4 + i;
            if (row < M) {
#pragma unroll
                for (int ni = 0; ni < 4; ni++) {
                    int col = wn * 64 + ni * 16 + lr;
                    ((__half*)Gout)[(size_t)row * 128 + col] = __float2half(acc2[mi][ni][i]);
                }
            }
        }
    }
}

// ---------------- launcher ----------------

extern "C" void kernel_launch(void* const* d_in, const int* in_sizes, int n_in,
                              void* d_out, int out_size, void* d_ws, size_t ws_size,
                              hipStream_t stream)
{
    const int N = in_sizes[0];
    const int E = in_sizes[1];
    const int* gate = (const int*)d_in[0];
    const int* src = (const int*)d_in[1];
    const int* dst = (const int*)d_in[2];
    const float* sidx = (const float*)d_in[3];
    const float* didx = (const float*)d_in[4];
    const float* rev = (const float*)d_in[5];
    const float* emb = (const float*)d_in[6];
    const float* w1[5] = {(const float*)d_in[7], (const float*)d_in[10], (const float*)d_in[13],
                          (const float*)d_in[16], (const float*)d_in[19]};
    const float* w2[5] = {(const float*)d_in[8], (const float*)d_in[11], (const float*)d_in[14],
                          (const float*)d_in[17], (const float*)d_in[20]};
    const float* b2[5] = {(const float*)d_in[9], (const float*)d_in[12], (const float*)d_in[15],
                          (const float*)d_in[18], (const float*)d_in[21]};

    char* ws = (char*)d_ws;
    size_t off = 0;
    auto alloc = [&](size_t bytes) {
        void* p = ws + off;
        off = (off + bytes + 255) & ~(size_t)255;
        return p;
    };
    u16* hb0 = (u16*)alloc((size_t)N * 128 * 2);
    u16* hb1 = (u16*)alloc((size_t)N * 128 * 2);
    u16* hN = (u16*)alloc((size_t)N * 128 * 2);
    u16* g = (u16*)alloc((size_t)N * 128 * 2);        // fp16
    int* cnt = (int*)alloc((size_t)N * 4);
    int* row_off = (int*)alloc((size_t)(N + 1) * 4);
    int* cursor = (int*)alloc((size_t)N * 4);
    int4* payload = (int4*)alloc((size_t)E * 16);
    int* partial = (int*)alloc(512 * 4);
    float* invd = (float*)alloc((size_t)N * 4);
    unsigned* w1h = (unsigned*)alloc(5 * 192 * 4);
    u16* w1b[5];
    u16* w2b[5];
    const int fis[5] = {64, 128, 128, 128, 128};
    for (int i = 0; i < 5; i++) w1b[i] = (u16*)alloc((size_t)128 * fis[i] * 2);
    for (int i = 0; i < 5; i++) {
        int fo = (i == 4) ? 64 : 128;
        w2b[i] = (u16*)alloc((size_t)fo * (fis[i] + 128) * 2);
    }

    WDesc wd;
    for (int i = 0; i < 5; i++) {
        wd.src[i] = w1[i]; wd.dst[i] = w1b[i];
        wd.scols[i] = fis[i] + 3; wd.dcols[i] = fis[i]; wd.n[i] = 128 * fis[i];
        int fo = (i == 4) ? 64 : 128;
        wd.src[5 + i] = w2[i]; wd.dst[5 + i] = w2b[i];
        wd.scols[5 + i] = fis[i] + 128; wd.dcols[5 + i] = fis[i] + 128;
        wd.n[5 + i] = fo * (fis[i] + 128);
    }
    k_wconv<<<dim3(128, 10), dim3(256), 0, stream>>>(wd);

    EDesc ed;
    for (int i = 0; i < 5; i++) {
        ed.src[i] = w1[i];
        ed.dst[i] = w1h + i * 192;
        ed.ldw[i] = fis[i] + 3;
        ed.fi[i] = fis[i];
    }
    k_wedge<<<dim3(5), dim3(192), 0, stream>>>(ed);

    hipMemsetAsync(cnt, 0, (size_t)N * 4, stream);
    k_count<<<dim3((E + 255) / 256), dim3(256), 0, stream>>>(dst, cnt, E);
    const int nb = (N + 255) / 256;
    k_scan1<<<dim3(nb), dim3(256), 0, stream>>>(cnt, partial, N);
    k_scan2<<<dim3(1), dim3(512), 0, stream>>>(partial, nb);
    k_scan3<<<dim3(nb), dim3(256), 0, stream>>>(cnt, partial, row_off, cursor, invd, N, E);
    k_scatter<<<dim3((E + 255) / 256), dim3(256), 0, stream>>>(dst, src, sidx, didx, rev, cursor, payload, E);
    k_emb<<<dim3((N * 64 + 255) / 256), dim3(256), 0, stream>>>(gate, emb, hb0, N);

    const int gg = (N + 127) / 128;
    const int eb = 2048;

    // ---- layer 1 (fi=64): g1 standalone, then fused W2+g2 ----
    k_mfma<64, 128, 64, 0, 0, 2><<<dim3(gg), dim3(256), 0, stream>>>(
        N, hb0, 64, (const u16*)nullptr, 0, w1b[0], (const float*)nullptr, g, 128);
    k_edge<<<dim3(eb), dim3(256), 0, stream>>>(N, row_off, payload, g, w1h + 0 * 192, invd, hN);
    k_mfma_fused<192, 64><<<dim3(gg), dim3(256), 0, stream>>>(
        N, hb0, 64, hN, 128, w2b[0], b2[0], hb1, w1b[1], g);

    // ---- layers 2..4: fused W2+g_next ----
    u16* hcur = hb1;
    u16* hnxt = hb0;
    for (int l = 1; l < 4; ++l) {
        k_edge<<<dim3(eb), dim3(256), 0, stream>>>(N, row_off, payload, g, w1h + l * 192, invd, hN);
        k_mfma_fused<256, 128><<<dim3(gg), dim3(256), 0, stream>>>(
            N, hcur, 128, hN, 128, w2b[l], b2[l], hnxt, w1b[l + 1], g);
        u16* tmp = hcur; hcur = hnxt; hnxt = tmp;
    }

    // ---- layer 5: edge + final W2 (out 64 fp32, no relu) ----
    k_edge<<<dim3(eb), dim3(256), 0, stream>>>(N, row_off, payload, g, w1h + 4 * 192, invd, hN);
    k_mfma<256, 64, 128, 1, 0, 0><<<dim3(gg), dim3(256), 0, stream>>>(
        N, hcur, 128, hN, 128, w2b[4], b2[4], (float*)d_out, 64);
}